// Round 14
// baseline (796.788 us; speedup 1.0000x reference)
//
#include <hip/hip_runtime.h>
#include <hip/hip_bf16.h>
#include <hip/hip_fp16.h>

typedef unsigned short u16;
typedef unsigned int u32;
typedef __attribute__((ext_vector_type(8))) short s16x8;
typedef __attribute__((ext_vector_type(8))) _Float16 f16x8;
typedef __attribute__((ext_vector_type(4))) float f32x4;
typedef __attribute__((ext_vector_type(2))) float f32x2;
typedef __attribute__((ext_vector_type(4))) unsigned short u16x4;

#define DEV static __device__ __forceinline__

// ---------- helpers ----------
DEV u16 bf16_rne(float f) {
  u32 u = __float_as_uint(f);
  u32 r = 0x7FFFu + ((u >> 16) & 1u);
  return (u16)((u + r) >> 16);
}
DEV float bf16_to_f32(u16 h) { return __uint_as_float(((u32)h) << 16); }

typedef const __attribute__((address_space(1))) u32* gptr_t;
typedef __attribute__((address_space(3))) u32* lptr_t;
DEV void gload_lds16(const void* g, void* l) {
  __builtin_amdgcn_global_load_lds((gptr_t)g, (lptr_t)l, 16, 0, 0);
}

// ---------- workspace layout (bytes) ----------
#define OFF_XSPLIT  0ull                 // 2 * 4096*2048 u16 (Xh|Xl) ; reused as obf (fp16)
#define OFF_WSPLIT  33554432ull          // 2 * 6144*2048 u16 (Wh|Wl) ; reused as pwh (fp16)
#define OFF_QKF     83886080ull          // 4096*4096 f32 ([q|k] fp32)
#define OFF_VB      150994944ull         // v bf16 (n,h,d)
#define OFF_QB      167772160ull         // q bf16 (h,n,d)
#define OFF_KB      184549376ull         // k bf16 (h,n,d)
#define OFF_VT      201326592ull         // v bf16 (h,d,n)
#define OFF_COS     218103808ull
#define OFF_SIN     219152384ull

// ---------- split fp32 -> bf16 hi + bf16 lo ----------
__global__ __launch_bounds__(256) void k_split(const float* __restrict__ in,
                                               u16* __restrict__ hi, u16* __restrict__ lo, int n) {
  int i = blockIdx.x * 256 + threadIdx.x;
  int stride = gridDim.x * 256;
  for (; i < n; i += stride) {
    float x = in[i];
    u16 h = bf16_rne(x);
    float xh = bf16_to_f32(h);
    hi[i] = h;
    lo[i] = bf16_rne(x - xh);
  }
}

// ---------- fp32 -> fp16 convert (RNE) ----------
__global__ __launch_bounds__(256) void k_cvt16(const float* __restrict__ in,
                                               u16* __restrict__ out, int n4) {
  int i = blockIdx.x * 256 + threadIdx.x;
  int stride = gridDim.x * 256;
  for (; i < n4; i += stride) {
    f32x4 v = *(const f32x4*)(in + (size_t)i * 4);
    u16x4 o;
#pragma unroll
    for (int j = 0; j < 4; ++j) {
      __half h = __float2half(v[j]);
      o[j] = *(u16*)&h;
    }
    *(u16x4*)(out + (size_t)i * 4) = o;
  }
}

// ---------- RoPE cos/sin table: (n, 64) ----------
__global__ __launch_bounds__(256) void k_rope_table(float* __restrict__ cosT, float* __restrict__ sinT) {
  int tid = blockIdx.x * 256 + threadIdx.x;
  if (tid >= 4096 * 64) return;
  int n = tid >> 6, j = tid & 63;
  int t = n >> 9, hh = (n >> 5) & 15, ww = n & 31;
  float pos, e;
  if (j < 32)      { pos = (float)t;  e = (float)j * (1.0f / 32.0f); }
  else if (j < 48) { pos = (float)hh; e = (float)(j - 32) * (1.0f / 16.0f); }
  else             { pos = (float)ww; e = (float)(j - 48) * (1.0f / 16.0f); }
  float inv = (float)pow(10000.0, -(double)e);
  float f = pos * inv;
  cosT[tid] = cosf(f);
  sinT[tid] = sinf(f);
}

// ---------- QKV GEMM: fused 3-segment bf16 hi/lo (Xh.Wh + Xh.Wl + Xl.Wh) ----------
__global__ __launch_bounds__(256, 2) void k_gemm_qkv(
    const u16* __restrict__ Ah_, const u16* __restrict__ Al_,
    const u16* __restrict__ Bh_, const u16* __restrict__ Bl_,
    const float* __restrict__ bias,
    float* __restrict__ outF, u16* __restrict__ outV)
{
  __shared__ u16 AsH[128 * 32];
  __shared__ u16 AsL[128 * 32];
  __shared__ u16 BsH[128 * 32];
  __shared__ u16 BsL[128 * 32];
  const int t = threadIdx.x;
  const int lane = t & 63;
  const int lr = lane & 15, lg = lane >> 4;
  const int w = t >> 6;
  const int wr = w >> 1, wc = w & 1;
  const int row0 = blockIdx.y * 128;
  const int col0 = blockIdx.x * 128;
  const int K = 2048;

  f32x4 acc[4][4];
#pragma unroll
  for (int m = 0; m < 4; m++)
#pragma unroll
    for (int n = 0; n < 4; n++) acc[m][n] = f32x4{0.f, 0.f, 0.f, 0.f};

  const int c0 = t, c1 = t + 256;
  const int kp0 = ((c0 & 3) ^ ((c0 >> 3) & 3)) * 8;
  const int kp1 = ((c1 & 3) ^ ((c1 >> 3) & 3)) * 8;
  const int slot8 = (lg ^ ((lr >> 1) & 3)) * 8;
  const size_t ar0 = (size_t)(row0 + (c0 >> 2)) * K;
  const size_t ar1 = (size_t)(row0 + (c1 >> 2)) * K;
  const size_t br0 = (size_t)(col0 + (c0 >> 2)) * K;
  const size_t br1 = (size_t)(col0 + (c1 >> 2)) * K;

  for (int kb = 0; kb < 64; ++kb) {
    const int k0 = kb * 32;
    gload_lds16(Ah_ + ar0 + k0 + kp0, &AsH[c0 * 8]);
    gload_lds16(Ah_ + ar1 + k0 + kp1, &AsH[c1 * 8]);
    gload_lds16(Al_ + ar0 + k0 + kp0, &AsL[c0 * 8]);
    gload_lds16(Al_ + ar1 + k0 + kp1, &AsL[c1 * 8]);
    gload_lds16(Bh_ + br0 + k0 + kp0, &BsH[c0 * 8]);
    gload_lds16(Bh_ + br1 + k0 + kp1, &BsH[c1 * 8]);
    gload_lds16(Bl_ + br0 + k0 + kp0, &BsL[c0 * 8]);
    gload_lds16(Bl_ + br1 + k0 + kp1, &BsL[c1 * 8]);
    __syncthreads();
    s16x8 ah[4], al[4], bh[4], bl[4];
#pragma unroll
    for (int m = 0; m < 4; m++) {
      ah[m] = *(const s16x8*)&AsH[(wr * 64 + m * 16 + lr) * 32 + slot8];
      al[m] = *(const s16x8*)&AsL[(wr * 64 + m * 16 + lr) * 32 + slot8];
    }
#pragma unroll
    for (int n = 0; n < 4; n++) {
      bh[n] = *(const s16x8*)&BsH[(wc * 64 + n * 16 + lr) * 32 + slot8];
      bl[n] = *(const s16x8*)&BsL[(wc * 64 + n * 16 + lr) * 32 + slot8];
    }
    __builtin_amdgcn_s_setprio(1);
#pragma unroll
    for (int m = 0; m < 4; m++)
#pragma unroll
      for (int n = 0; n < 4; n++) {
        acc[m][n] = __builtin_amdgcn_mfma_f32_16x16x32_bf16(ah[m], bh[n], acc[m][n], 0, 0, 0);
        acc[m][n] = __builtin_amdgcn_mfma_f32_16x16x32_bf16(ah[m], bl[n], acc[m][n], 0, 0, 0);
        acc[m][n] = __builtin_amdgcn_mfma_f32_16x16x32_bf16(al[m], bh[n], acc[m][n], 0, 0, 0);
      }
    __builtin_amdgcn_s_setprio(0);
    __syncthreads();
  }

#pragma unroll
  for (int m = 0; m < 4; m++) {
#pragma unroll
    for (int n = 0; n < 4; n++) {
      int col = col0 + wc * 64 + n * 16 + lr;
      float b = bias[col];
#pragma unroll
      for (int r = 0; r < 4; r++) {
        int row = row0 + wr * 64 + m * 16 + lg * 4 + r;
        float v = acc[m][n][r] + b;
        if (col < 4096) outF[(size_t)row * 4096 + col] = v;
        else            outV[(size_t)row * 2048 + (col - 4096)] = bf16_rne(v);
      }
    }
  }
}

// ---------- proj GEMM: fp16 single segment (o is bf16-exact in fp16; only w rounded) ----------
__global__ __launch_bounds__(256, 2) void k_gemm_proj(
    const u16* __restrict__ A, const u16* __restrict__ B,
    const float* __restrict__ bias, float* __restrict__ outF)
{
  __shared__ u16 As[128 * 32];
  __shared__ u16 Bs[128 * 32];
  const int t = threadIdx.x;
  const int lane = t & 63;
  const int lr = lane & 15, lg = lane >> 4;
  const int w = t >> 6;
  const int wr = w >> 1, wc = w & 1;
  const int row0 = blockIdx.y * 128;
  const int col0 = blockIdx.x * 128;
  const int K = 2048;

  f32x4 acc[4][4];
#pragma unroll
  for (int m = 0; m < 4; m++)
#pragma unroll
    for (int n = 0; n < 4; n++) acc[m][n] = f32x4{0.f, 0.f, 0.f, 0.f};

  const int c0 = t, c1 = t + 256;
  const int kp0 = ((c0 & 3) ^ ((c0 >> 3) & 3)) * 8;
  const int kp1 = ((c1 & 3) ^ ((c1 >> 3) & 3)) * 8;
  const int slot8 = (lg ^ ((lr >> 1) & 3)) * 8;

  for (int kb = 0; kb < 64; ++kb) {
    const int k0 = kb * 32;
    gload_lds16(A + (size_t)(row0 + (c0 >> 2)) * K + k0 + kp0, &As[c0 * 8]);
    gload_lds16(A + (size_t)(row0 + (c1 >> 2)) * K + k0 + kp1, &As[c1 * 8]);
    gload_lds16(B + (size_t)(col0 + (c0 >> 2)) * K + k0 + kp0, &Bs[c0 * 8]);
    gload_lds16(B + (size_t)(col0 + (c1 >> 2)) * K + k0 + kp1, &Bs[c1 * 8]);
    __syncthreads();
    f16x8 af[4], bf[4];
#pragma unroll
    for (int m = 0; m < 4; m++)
      af[m] = *(const f16x8*)&As[(wr * 64 + m * 16 + lr) * 32 + slot8];
#pragma unroll
    for (int n = 0; n < 4; n++)
      bf[n] = *(const f16x8*)&Bs[(wc * 64 + n * 16 + lr) * 32 + slot8];
    __builtin_amdgcn_s_setprio(1);
#pragma unroll
    for (int m = 0; m < 4; m++)
#pragma unroll
      for (int n = 0; n < 4; n++)
        acc[m][n] = __builtin_amdgcn_mfma_f32_16x16x32_f16(af[m], bf[n], acc[m][n], 0, 0, 0);
    __builtin_amdgcn_s_setprio(0);
    __syncthreads();
  }

#pragma unroll
  for (int m = 0; m < 4; m++) {
#pragma unroll
    for (int n = 0; n < 4; n++) {
      int col = col0 + wc * 64 + n * 16 + lr;
      float b = bias[col];
#pragma unroll
      for (int r = 0; r < 4; r++) {
        int row = row0 + wr * 64 + m * 16 + lg * 4 + r;
        outF[(size_t)row * 2048 + col] = acc[m][n][r] + b;
      }
    }
  }
}

// ---------- RMSNorm (fp32) + RoPE + bf16 cast for q,k. One wave per (n,h). ----------
__global__ __launch_bounds__(256) void k_norm_rope(
    const float* __restrict__ qkf, const float* __restrict__ qw, const float* __restrict__ kw,
    const float* __restrict__ cosT, const float* __restrict__ sinT,
    u16* __restrict__ qb, u16* __restrict__ kb)
{
  int gw = (blockIdx.x * 256 + threadIdx.x) >> 6;
  int lane = threadIdx.x & 63;
  int n = gw >> 4;
  int h = gw & 15;
  float c = cosT[n * 64 + lane];
  float s = sinT[n * 64 + lane];
#pragma unroll
  for (int p = 0; p < 2; ++p) {
    const float* src = qkf + (size_t)n * 4096 + p * 2048 + h * 128;
    f32x2 xv = *(const f32x2*)(src + lane * 2);
    float xr = xv[0], xi = xv[1];
    float ss = xr * xr + xi * xi;
#pragma unroll
    for (int m = 1; m < 64; m <<= 1) ss += __shfl_xor(ss, m, 64);
    float r = 1.0f / sqrtf(ss * (1.0f / 128.0f) + 1e-6f);
    const float* wgt = p ? kw : qw;
    float yr = xr * r * wgt[lane * 2];
    float yi = xi * r * wgt[lane * 2 + 1];
    float o0 = yr * c - yi * s;
    float o1 = yr * s + yi * c;
    u16* dst = (p ? kb : qb) + (size_t)h * 4096 * 128 + (size_t)n * 128 + lane * 2;
    *(u32*)dst = ((u32)bf16_rne(o1) << 16) | bf16_rne(o0);
  }
}

// ---------- V transpose: (n, h*128+d) -> (h, d, n) ----------
__global__ __launch_bounds__(256) void k_transpose_v(const u16* __restrict__ vb, u16* __restrict__ vt) {
  __shared__ u16 Vs[64][136];
  int h = blockIdx.y;
  int n0 = blockIdx.x * 64;
  int t = threadIdx.x;
  int nl = t >> 2, d0 = (t & 3) * 32;
  const u16* src = vb + (size_t)(n0 + nl) * 2048 + h * 128 + d0;
#pragma unroll
  for (int i = 0; i < 8; ++i)
    *(u16x4*)&Vs[nl][d0 + i * 4] = *(const u16x4*)(src + i * 4);
  __syncthreads();
  int d = t >> 1, nc = (t & 1) * 32;
  u16* dst = vt + (size_t)h * 128 * 4096 + (size_t)d * 4096 + n0 + nc;
#pragma unroll
  for (int j4 = 0; j4 < 8; ++j4) {
    u16x4 o;
    o.x = Vs[nc + j4 * 4 + 0][d];
    o.y = Vs[nc + j4 * 4 + 1][d];
    o.z = Vs[nc + j4 * 4 + 2][d];
    o.w = Vs[nc + j4 * 4 + 3][d];
    *(u16x4*)(dst + j4 * 4) = o;
  }
}

// ---------- flash attention: same phase-locked sync skeleton as r8/r12, smaller tiles ----------
// 256 threads / 4 waves x 16 q-rows (block = 64 q-rows), KVBLK = 32, grid 1024 (head-local XCD).
// LDS = Ks[2]8K + Vs[2]8K + Ps4K = 36 KB -> 4 blocks/CU = 16 waves/CU (2x round-12 occupancy).
// Sync structure byte-identical to the proven r8/r12 kernel: stage(kt+1) at top, one full-drain
// __syncthreads at iter end (keeps blocks phase-locked -> K/V served from L2, FETCH ~30 MB).
__global__ __launch_bounds__(256, 4) void k_attn(
    const u16* __restrict__ qb, const u16* __restrict__ kb, const u16* __restrict__ vt,
    u16* __restrict__ obf)
{
  __shared__ u16 Ks[2][32 * 128];   // row-XOR swizzled (row&7)
  __shared__ u16 Vs[2][128 * 32];   // chunk-XOR swizzled ((d>>1)&3)
  __shared__ u16 Ps[4][16 * 32];    // per-wave P, chunk-XOR swizzled (row>>2)&3
  const int t = threadIdx.x;
  const int lane = t & 63;
  const int lr = lane & 15, lg = lane >> 4;
  const int w = t >> 6;

  // head-local XCD mapping: bid%8 -> XCD; per XCD two heads (c, c+8)
  const int bid = blockIdx.x;                 // 0..1023
  const int h = (bid & 7) + 8 * (bid >> 9);   // 0..15
  const int qt = (bid >> 3) & 63;             // 0..63
  const int qw0 = qt * 64 + w * 16;

  const u16* qh = qb + (size_t)h * 4096 * 128;
  const u16* kh = kb + (size_t)h * 4096 * 128;
  const u16* vh = vt + (size_t)h * 128 * 4096;

  s16x8 qf[4];
#pragma unroll
  for (int ks = 0; ks < 4; ++ks)
    qf[ks] = *(const s16x8*)(qh + (size_t)(qw0 + lr) * 128 + ks * 32 + lg * 8);

  f32x4 oacc[8];
#pragma unroll
  for (int j = 0; j < 8; j++) oacc[j] = f32x4{0.f, 0.f, 0.f, 0.f};
  float M[4], L[4];
#pragma unroll
  for (int r = 0; r < 4; r++) { M[r] = -__builtin_inff(); L[r] = 0.f; }

  const float scale_bf = bf16_to_f32(bf16_rne(0.08838834764831845f));

  auto stageKV = [&](int kt, int b) __attribute__((always_inline)) {
    // K tile: 32 rows x 128 d = 8 KB = 512 chunks
#pragma unroll
    for (int i = 0; i < 2; ++i) {
      int c = t + i * 256;
      int row = c >> 4;
      int cc = (c & 15) ^ (row & 7);
      gload_lds16(kh + (size_t)(kt * 32 + row) * 128 + cc * 8, &Ks[b][c * 8]);
    }
    // V tile: 128 d-rows x 32 keys = 8 KB = 512 chunks (4 chunks/row)
#pragma unroll
    for (int i = 0; i < 2; ++i) {
      int c = t + i * 256;
      int d = c >> 2;
      int cc = (c & 3) ^ ((d >> 1) & 3);
      gload_lds16(vh + (size_t)d * 4096 + kt * 32 + cc * 8, &Vs[b][c * 8]);
    }
  };

  stageKV(0, 0);
  __syncthreads();

  for (int kt = 0; kt < 128; ++kt) {
    const int b = kt & 1;
    if (kt + 1 < 128) stageKV(kt + 1, b ^ 1);   // hides under compute; drained at end-of-iter sync

    // S = Q . K^T from Ks[b]  (row stride 256 B, same read swizzle as r12)
    f32x4 sfr[2];
    __builtin_amdgcn_s_setprio(1);
#pragma unroll
    for (int kbl = 0; kbl < 2; ++kbl) {
      f32x4 a = f32x4{0.f, 0.f, 0.f, 0.f};
#pragma unroll
      for (int ks = 0; ks < 4; ++ks) {
        int key = kbl * 16 + lr;
        int byteoff = (key * 256 + (ks * 32 + lg * 8) * 2) ^ ((key & 7) << 4);
        s16x8 kfr = *(const s16x8*)((const char*)&Ks[b][0] + byteoff);
        a = __builtin_amdgcn_mfma_f32_16x16x32_bf16(qf[ks], kfr, a, 0, 0, 0);
      }
      sfr[kbl] = a;
    }
    __builtin_amdgcn_s_setprio(0);

    // online softmax (double-rounded bf16 scores, native exp, defer-max THR=8)
    float mx[4];
#pragma unroll
    for (int r = 0; r < 4; ++r) {
#pragma unroll
      for (int kbl = 0; kbl < 2; ++kbl) {
        float sv = bf16_to_f32(bf16_rne(sfr[kbl][r])) * scale_bf;
        sfr[kbl][r] = bf16_to_f32(bf16_rne(sv));
      }
      float m0 = fmaxf(sfr[0][r], sfr[1][r]);
#pragma unroll
      for (int m = 1; m < 16; m <<= 1) m0 = fmaxf(m0, __shfl_xor(m0, m, 64));
      mx[r] = m0;
    }
    bool ok = (mx[0] - M[0] <= 8.f) && (mx[1] - M[1] <= 8.f) &&
              (mx[2] - M[2] <= 8.f) && (mx[3] - M[3] <= 8.f);
    if (!__all(ok)) {
#pragma unroll
      for (int r = 0; r < 4; ++r) {
        float nm = fmaxf(M[r], mx[r]);
        float fac = __expf(M[r] - nm);
        M[r] = nm;
        L[r] *= fac;
#pragma unroll
        for (int db = 0; db < 8; ++db) oacc[db][r] *= fac;
      }
    }
    float sum[4] = {0.f, 0.f, 0.f, 0.f};
#pragma unroll
    for (int kbl = 0; kbl < 2; ++kbl)
#pragma unroll
      for (int r = 0; r < 4; ++r) {
        float p = __expf(sfr[kbl][r] - M[r]);
        sum[r] += p;
        int prow = lg * 4 + r;   // (prow>>2)&3 == lg
        Ps[w][prow * 32 + ((kbl * 16 + lr) ^ (lg << 3))] = bf16_rne(p);
      }
#pragma unroll
    for (int r = 0; r < 4; ++r) {
      float s4 = sum[r];
#pragma unroll
      for (int m = 1; m < 16; m <<= 1) s4 += __shfl_xor(s4, m, 64);
      L[r] += s4;
    }

    asm volatile("s_waitcnt lgkmcnt(0)" ::: "memory");   // own-wave P writes visible

    // PV: O += P (16x32) . V (32x128) from Vs[b]
    s16x8 pa = *(const s16x8*)&Ps[w][lr * 32 + ((lg * 8) ^ (((lr >> 2) & 3) << 3))];
    __builtin_amdgcn_s_setprio(1);
#pragma unroll
    for (int db = 0; db < 8; ++db) {
      int d = db * 16 + lr;
      int byteoff = (d * 64 + lg * 16) ^ (((d >> 1) & 3) << 4);
      s16x8 vf = *(const s16x8*)((const char*)&Vs[b][0] + byteoff);
      oacc[db] = __builtin_amdgcn_mfma_f32_16x16x32_bf16(pa, vf, oacc[db], 0, 0, 0);
    }
    __builtin_amdgcn_s_setprio(0);
    __syncthreads();   // full drain (phase lock) -> next buffer ready, prev buffer free
  }

  // normalize + round to bf16 (matches ref) + store as FP16 bits (exact bf16->fp16)
  float rl[4];
#pragma unroll
  for (int r = 0; r < 4; ++r) rl[r] = 1.0f / L[r];
#pragma unroll
  for (int db = 0; db < 8; ++db) {
    int d = db * 16 + lr;
#pragma unroll
    for (int r = 0; r < 4; ++r) {
      int q = qw0 + lg * 4 + r;
      float obf16 = bf16_to_f32(bf16_rne(oacc[db][r] * rl[r]));
      __half hh = __float2half(obf16);
      obf[(size_t)q * 2048 + h * 128 + d] = *(u16*)&hh;
    }
  }
}

// ---------- launch ----------
extern "C" void kernel_launch(void* const* d_in, const int* in_sizes, int n_in,
                              void* d_out, int out_size, void* d_ws, size_t ws_size,
                              hipStream_t stream) {
  const float* x      = (const float*)d_in[0];
  const float* qkv_w  = (const float*)d_in[1];
  const float* qkv_b  = (const float*)d_in[2];
  const float* qnw    = (const float*)d_in[3];
  const float* knw    = (const float*)d_in[4];
  const float* proj_w = (const float*)d_in[5];
  const float* proj_b = (const float*)d_in[6];
  float* out = (float*)d_out;
  char* ws = (char*)d_ws;

  u16* xs    = (u16*)(ws + OFF_XSPLIT);
  u16* wsp   = (u16*)(ws + OFF_WSPLIT);
  u16* pwh   = (u16*)(ws + OFF_WSPLIT);   // fp16 proj_w, reuse after QKV GEMM
  float* qkf = (float*)(ws + OFF_QKF);
  u16* vb16  = (u16*)(ws + OFF_VB);
  u16* qb16  = (u16*)(ws + OFF_QB);
  u16* kb16  = (u16*)(ws + OFF_KB);
  u16* vt16  = (u16*)(ws + OFF_VT);
  u16* obf   = (u16*)(ws + OFF_XSPLIT);   // fp16 o, reuse (x splits dead after QKV GEMM)
  float* cosT = (float*)(ws + OFF_COS);
  float* sinT = (float*)(ws + OFF_SIN);

  u16* xsl = xs + (size_t)4096 * 2048;
  u16* wl  = wsp + (size_t)6144 * 2048;

  k_split<<<2048, 256, 0, stream>>>(x, xs, xsl, 4096 * 2048);
  k_split<<<2048, 256, 0, stream>>>(qkv_w, wsp, wl, 6144 * 2048);
  k_rope_table<<<1024, 256, 0, stream>>>(cosT, sinT);

  // QKV: fused 3-segment bf16 hi/lo
  k_gemm_qkv<<<dim3(48, 32), 256, 0, stream>>>(xs, xsl, wsp, wl, qkv_b, qkf, vb16);

  k_cvt16<<<2048, 256, 0, stream>>>(proj_w, pwh, 2048 * 2048 / 4);
  k_norm_rope<<<16384, 256, 0, stream>>>(qkf, qnw, knw, cosT, sinT, qb16, kb16);
  k_transpose_v<<<dim3(64, 16), 256, 0, stream>>>(vb16, vt16);
  k_attn<<<1024, 256, 0, stream>>>(qb16, kb16, vt16, obf);

  // proj: fp16 single segment
  k_gemm_proj<<<dim3(16, 32), 256, 0, stream>>>(obf, pwh, proj_b, out);
}

// Round 16
// 602.944 us; speedup vs baseline: 1.3215x; 1.3215x over previous
//
#include <hip/hip_runtime.h>
#include <hip/hip_bf16.h>
#include <hip/hip_fp16.h>

typedef unsigned short u16;
typedef unsigned int u32;
typedef __attribute__((ext_vector_type(8))) short s16x8;
typedef __attribute__((ext_vector_type(8))) _Float16 f16x8;
typedef __attribute__((ext_vector_type(4))) float f32x4;
typedef __attribute__((ext_vector_type(2))) float f32x2;
typedef __attribute__((ext_vector_type(4))) unsigned short u16x4;

#define DEV static __device__ __forceinline__

// ---------- helpers ----------
DEV u16 bf16_rne(float f) {
  u32 u = __float_as_uint(f);
  u32 r = 0x7FFFu + ((u >> 16) & 1u);
  return (u16)((u + r) >> 16);
}
DEV float bf16_to_f32(u16 h) { return __uint_as_float(((u32)h) << 16); }

typedef const __attribute__((address_space(1))) u32* gptr_t;
typedef __attribute__((address_space(3))) u32* lptr_t;
DEV void gload_lds16(const void* g, void* l) {
  __builtin_amdgcn_global_load_lds((gptr_t)g, (lptr_t)l, 16, 0, 0);
}

// ---------- workspace layout (bytes) ----------
#define OFF_XSPLIT  0ull                 // 2 * 4096*2048 u16 (Xh|Xl) ; reused as obf (fp16)
#define OFF_WSPLIT  33554432ull          // 2 * 6144*2048 u16 (Wh|Wl) ; reused as pwh (fp16)
#define OFF_QKF     83886080ull          // 4096*4096 f32 ([q|k] fp32)
#define OFF_VB      150994944ull         // v bf16 (n,h,d)
#define OFF_QB      167772160ull         // q bf16 (h,n,d)
#define OFF_KB      184549376ull         // k bf16 (h,n,d)
#define OFF_VT      201326592ull         // v bf16 (h,d,n)
#define OFF_COS     218103808ull
#define OFF_SIN     219152384ull

// ---------- split fp32 -> bf16 hi + bf16 lo ----------
__global__ __launch_bounds__(256) void k_split(const float* __restrict__ in,
                                               u16* __restrict__ hi, u16* __restrict__ lo, int n) {
  int i = blockIdx.x * 256 + threadIdx.x;
  int stride = gridDim.x * 256;
  for (; i < n; i += stride) {
    float x = in[i];
    u16 h = bf16_rne(x);
    float xh = bf16_to_f32(h);
    hi[i] = h;
    lo[i] = bf16_rne(x - xh);
  }
}

// ---------- fp32 -> fp16 convert (RNE) ----------
__global__ __launch_bounds__(256) void k_cvt16(const float* __restrict__ in,
                                               u16* __restrict__ out, int n4) {
  int i = blockIdx.x * 256 + threadIdx.x;
  int stride = gridDim.x * 256;
  for (; i < n4; i += stride) {
    f32x4 v = *(const f32x4*)(in + (size_t)i * 4);
    u16x4 o;
#pragma unroll
    for (int j = 0; j < 4; ++j) {
      __half h = __float2half(v[j]);
      o[j] = *(u16*)&h;
    }
    *(u16x4*)(out + (size_t)i * 4) = o;
  }
}

// ---------- RoPE cos/sin table: (n, 64) ----------
__global__ __launch_bounds__(256) void k_rope_table(float* __restrict__ cosT, float* __restrict__ sinT) {
  int tid = blockIdx.x * 256 + threadIdx.x;
  if (tid >= 4096 * 64) return;
  int n = tid >> 6, j = tid & 63;
  int t = n >> 9, hh = (n >> 5) & 15, ww = n & 31;
  float pos, e;
  if (j < 32)      { pos = (float)t;  e = (float)j * (1.0f / 32.0f); }
  else if (j < 48) { pos = (float)hh; e = (float)(j - 32) * (1.0f / 16.0f); }
  else             { pos = (float)ww; e = (float)(j - 48) * (1.0f / 16.0f); }
  float inv = (float)pow(10000.0, -(double)e);
  float f = pos * inv;
  cosT[tid] = cosf(f);
  sinT[tid] = sinf(f);
}

// ---------- QKV GEMM: fused 3-segment bf16 hi/lo (Xh.Wh + Xh.Wl + Xl.Wh) ----------
__global__ __launch_bounds__(256, 2) void k_gemm_qkv(
    const u16* __restrict__ Ah_, const u16* __restrict__ Al_,
    const u16* __restrict__ Bh_, const u16* __restrict__ Bl_,
    const float* __restrict__ bias,
    float* __restrict__ outF, u16* __restrict__ outV)
{
  __shared__ u16 AsH[128 * 32];
  __shared__ u16 AsL[128 * 32];
  __shared__ u16 BsH[128 * 32];
  __shared__ u16 BsL[128 * 32];
  const int t = threadIdx.x;
  const int lane = t & 63;
  const int lr = lane & 15, lg = lane >> 4;
  const int w = t >> 6;
  const int wr = w >> 1, wc = w & 1;
  const int row0 = blockIdx.y * 128;
  const int col0 = blockIdx.x * 128;
  const int K = 2048;

  f32x4 acc[4][4];
#pragma unroll
  for (int m = 0; m < 4; m++)
#pragma unroll
    for (int n = 0; n < 4; n++) acc[m][n] = f32x4{0.f, 0.f, 0.f, 0.f};

  const int c0 = t, c1 = t + 256;
  const int kp0 = ((c0 & 3) ^ ((c0 >> 3) & 3)) * 8;
  const int kp1 = ((c1 & 3) ^ ((c1 >> 3) & 3)) * 8;
  const int slot8 = (lg ^ ((lr >> 1) & 3)) * 8;
  const size_t ar0 = (size_t)(row0 + (c0 >> 2)) * K;
  const size_t ar1 = (size_t)(row0 + (c1 >> 2)) * K;
  const size_t br0 = (size_t)(col0 + (c0 >> 2)) * K;
  const size_t br1 = (size_t)(col0 + (c1 >> 2)) * K;

  for (int kb = 0; kb < 64; ++kb) {
    const int k0 = kb * 32;
    gload_lds16(Ah_ + ar0 + k0 + kp0, &AsH[c0 * 8]);
    gload_lds16(Ah_ + ar1 + k0 + kp1, &AsH[c1 * 8]);
    gload_lds16(Al_ + ar0 + k0 + kp0, &AsL[c0 * 8]);
    gload_lds16(Al_ + ar1 + k0 + kp1, &AsL[c1 * 8]);
    gload_lds16(Bh_ + br0 + k0 + kp0, &BsH[c0 * 8]);
    gload_lds16(Bh_ + br1 + k0 + kp1, &BsH[c1 * 8]);
    gload_lds16(Bl_ + br0 + k0 + kp0, &BsL[c0 * 8]);
    gload_lds16(Bl_ + br1 + k0 + kp1, &BsL[c1 * 8]);
    __syncthreads();
    s16x8 ah[4], al[4], bh[4], bl[4];
#pragma unroll
    for (int m = 0; m < 4; m++) {
      ah[m] = *(const s16x8*)&AsH[(wr * 64 + m * 16 + lr) * 32 + slot8];
      al[m] = *(const s16x8*)&AsL[(wr * 64 + m * 16 + lr) * 32 + slot8];
    }
#pragma unroll
    for (int n = 0; n < 4; n++) {
      bh[n] = *(const s16x8*)&BsH[(wc * 64 + n * 16 + lr) * 32 + slot8];
      bl[n] = *(const s16x8*)&BsL[(wc * 64 + n * 16 + lr) * 32 + slot8];
    }
    __builtin_amdgcn_s_setprio(1);
#pragma unroll
    for (int m = 0; m < 4; m++)
#pragma unroll
      for (int n = 0; n < 4; n++) {
        acc[m][n] = __builtin_amdgcn_mfma_f32_16x16x32_bf16(ah[m], bh[n], acc[m][n], 0, 0, 0);
        acc[m][n] = __builtin_amdgcn_mfma_f32_16x16x32_bf16(ah[m], bl[n], acc[m][n], 0, 0, 0);
        acc[m][n] = __builtin_amdgcn_mfma_f32_16x16x32_bf16(al[m], bh[n], acc[m][n], 0, 0, 0);
      }
    __builtin_amdgcn_s_setprio(0);
    __syncthreads();
  }

#pragma unroll
  for (int m = 0; m < 4; m++) {
#pragma unroll
    for (int n = 0; n < 4; n++) {
      int col = col0 + wc * 64 + n * 16 + lr;
      float b = bias[col];
#pragma unroll
      for (int r = 0; r < 4; r++) {
        int row = row0 + wr * 64 + m * 16 + lg * 4 + r;
        float v = acc[m][n][r] + b;
        if (col < 4096) outF[(size_t)row * 4096 + col] = v;
        else            outV[(size_t)row * 2048 + (col - 4096)] = bf16_rne(v);
      }
    }
  }
}

// ---------- proj GEMM: fp16 single segment (o is bf16-exact in fp16; only w rounded) ----------
__global__ __launch_bounds__(256, 2) void k_gemm_proj(
    const u16* __restrict__ A, const u16* __restrict__ B,
    const float* __restrict__ bias, float* __restrict__ outF)
{
  __shared__ u16 As[128 * 32];
  __shared__ u16 Bs[128 * 32];
  const int t = threadIdx.x;
  const int lane = t & 63;
  const int lr = lane & 15, lg = lane >> 4;
  const int w = t >> 6;
  const int wr = w >> 1, wc = w & 1;
  const int row0 = blockIdx.y * 128;
  const int col0 = blockIdx.x * 128;
  const int K = 2048;

  f32x4 acc[4][4];
#pragma unroll
  for (int m = 0; m < 4; m++)
#pragma unroll
    for (int n = 0; n < 4; n++) acc[m][n] = f32x4{0.f, 0.f, 0.f, 0.f};

  const int c0 = t, c1 = t + 256;
  const int kp0 = ((c0 & 3) ^ ((c0 >> 3) & 3)) * 8;
  const int kp1 = ((c1 & 3) ^ ((c1 >> 3) & 3)) * 8;
  const int slot8 = (lg ^ ((lr >> 1) & 3)) * 8;

  for (int kb = 0; kb < 64; ++kb) {
    const int k0 = kb * 32;
    gload_lds16(A + (size_t)(row0 + (c0 >> 2)) * K + k0 + kp0, &As[c0 * 8]);
    gload_lds16(A + (size_t)(row0 + (c1 >> 2)) * K + k0 + kp1, &As[c1 * 8]);
    gload_lds16(B + (size_t)(col0 + (c0 >> 2)) * K + k0 + kp0, &Bs[c0 * 8]);
    gload_lds16(B + (size_t)(col0 + (c1 >> 2)) * K + k0 + kp1, &Bs[c1 * 8]);
    __syncthreads();
    f16x8 af[4], bf[4];
#pragma unroll
    for (int m = 0; m < 4; m++)
      af[m] = *(const f16x8*)&As[(wr * 64 + m * 16 + lr) * 32 + slot8];
#pragma unroll
    for (int n = 0; n < 4; n++)
      bf[n] = *(const f16x8*)&Bs[(wc * 64 + n * 16 + lr) * 32 + slot8];
    __builtin_amdgcn_s_setprio(1);
#pragma unroll
    for (int m = 0; m < 4; m++)
#pragma unroll
      for (int n = 0; n < 4; n++)
        acc[m][n] = __builtin_amdgcn_mfma_f32_16x16x32_f16(af[m], bf[n], acc[m][n], 0, 0, 0);
    __builtin_amdgcn_s_setprio(0);
    __syncthreads();
  }

#pragma unroll
  for (int m = 0; m < 4; m++) {
#pragma unroll
    for (int n = 0; n < 4; n++) {
      int col = col0 + wc * 64 + n * 16 + lr;
      float b = bias[col];
#pragma unroll
      for (int r = 0; r < 4; r++) {
        int row = row0 + wr * 64 + m * 16 + lg * 4 + r;
        outF[(size_t)row * 2048 + col] = acc[m][n][r] + b;
      }
    }
  }
}

// ---------- RMSNorm (fp32) + RoPE + bf16 cast for q,k. One wave per (n,h). ----------
__global__ __launch_bounds__(256) void k_norm_rope(
    const float* __restrict__ qkf, const float* __restrict__ qw, const float* __restrict__ kw,
    const float* __restrict__ cosT, const float* __restrict__ sinT,
    u16* __restrict__ qb, u16* __restrict__ kb)
{
  int gw = (blockIdx.x * 256 + threadIdx.x) >> 6;
  int lane = threadIdx.x & 63;
  int n = gw >> 4;
  int h = gw & 15;
  float c = cosT[n * 64 + lane];
  float s = sinT[n * 64 + lane];
#pragma unroll
  for (int p = 0; p < 2; ++p) {
    const float* src = qkf + (size_t)n * 4096 + p * 2048 + h * 128;
    f32x2 xv = *(const f32x2*)(src + lane * 2);
    float xr = xv[0], xi = xv[1];
    float ss = xr * xr + xi * xi;
#pragma unroll
    for (int m = 1; m < 64; m <<= 1) ss += __shfl_xor(ss, m, 64);
    float r = 1.0f / sqrtf(ss * (1.0f / 128.0f) + 1e-6f);
    const float* wgt = p ? kw : qw;
    float yr = xr * r * wgt[lane * 2];
    float yi = xi * r * wgt[lane * 2 + 1];
    float o0 = yr * c - yi * s;
    float o1 = yr * s + yi * c;
    u16* dst = (p ? kb : qb) + (size_t)h * 4096 * 128 + (size_t)n * 128 + lane * 2;
    *(u32*)dst = ((u32)bf16_rne(o1) << 16) | bf16_rne(o0);
  }
}

// ---------- V transpose: (n, h*128+d) -> (h, d, n) ----------
__global__ __launch_bounds__(256) void k_transpose_v(const u16* __restrict__ vb, u16* __restrict__ vt) {
  __shared__ u16 Vs[64][136];
  int h = blockIdx.y;
  int n0 = blockIdx.x * 64;
  int t = threadIdx.x;
  int nl = t >> 2, d0 = (t & 3) * 32;
  const u16* src = vb + (size_t)(n0 + nl) * 2048 + h * 128 + d0;
#pragma unroll
  for (int i = 0; i < 8; ++i)
    *(u16x4*)&Vs[nl][d0 + i * 4] = *(const u16x4*)(src + i * 4);
  __syncthreads();
  int d = t >> 1, nc = (t & 1) * 32;
  u16* dst = vt + (size_t)h * 128 * 4096 + (size_t)d * 4096 + n0 + nc;
#pragma unroll
  for (int j4 = 0; j4 < 8; ++j4) {
    u16x4 o;
    o.x = Vs[nc + j4 * 4 + 0][d];
    o.y = Vs[nc + j4 * 4 + 1][d];
    o.z = Vs[nc + j4 * 4 + 2][d];
    o.w = Vs[nc + j4 * 4 + 3][d];
    *(u16x4*)(dst + j4 * 4) = o;
  }
}

// ---------- flash attention: r12 proven skeleton, no-max softmax (hand-rolled RNE only) ----------
// rmsnorm'd q,k bound |s*scale| <= 128*0.0884 ~ 11.3 -> exp(s) <= 9e4, L <= 3.7e8: no overflow.
// exp(max) cancels in the final 1/L; L partials per-lane, reduced ONCE after the loop.
__global__ __launch_bounds__(256, 2) void k_attn(
    const u16* __restrict__ qb, const u16* __restrict__ kb, const u16* __restrict__ vt,
    u16* __restrict__ obf)
{
  __shared__ u16 Ks[2][64 * 128];
  __shared__ u16 Vs[2][128 * 64];
  __shared__ u16 Ps[4][32 * 64];
  const int t = threadIdx.x;
  const int lane = t & 63;
  const int lr = lane & 15, lg = lane >> 4;
  const int w = t >> 6;

  const int bid = blockIdx.y * 32 + blockIdx.x;
  const int h = (bid & 7) + 8 * ((bid >> 3) >> 5);
  const int qt = (bid >> 3) & 31;
  const int qw0 = qt * 128 + w * 32;

  const u16* qh = qb + (size_t)h * 4096 * 128;
  const u16* kh = kb + (size_t)h * 4096 * 128;
  const u16* vh = vt + (size_t)h * 128 * 4096;

  s16x8 qf[2][4];
#pragma unroll
  for (int qi = 0; qi < 2; ++qi)
#pragma unroll
    for (int ks = 0; ks < 4; ++ks)
      qf[qi][ks] = *(const s16x8*)(qh + (size_t)(qw0 + qi * 16 + lr) * 128 + ks * 32 + lg * 8);

  f32x4 oacc[2][8];
#pragma unroll
  for (int i = 0; i < 2; i++)
#pragma unroll
    for (int j = 0; j < 8; j++) oacc[i][j] = f32x4{0.f, 0.f, 0.f, 0.f};
  float Lp[2][4];
#pragma unroll
  for (int i = 0; i < 2; i++)
#pragma unroll
    for (int r = 0; r < 4; r++) Lp[i][r] = 0.f;

  const float scale_bf = bf16_to_f32(bf16_rne(0.08838834764831845f));

  auto stageKV = [&](int kt, int b) __attribute__((always_inline)) {
#pragma unroll
    for (int i = 0; i < 4; ++i) {
      int c = t + i * 256;
      int row = c >> 4;
      int cc = (c & 15) ^ (row & 7);
      gload_lds16(kh + (size_t)(kt * 64 + row) * 128 + cc * 8, &Ks[b][c * 8]);
    }
#pragma unroll
    for (int i = 0; i < 4; ++i) {
      int c = t + i * 256;
      int d = c >> 3;
      int cc = (c & 7) ^ (d & 7);
      gload_lds16(vh + (size_t)d * 4096 + kt * 64 + cc * 8, &Vs[b][c * 8]);
    }
  };

  stageKV(0, 0);
  __syncthreads();

  for (int kt = 0; kt < 64; ++kt) {
    const int b = kt & 1;
    if (kt + 1 < 64) stageKV(kt + 1, b ^ 1);

    f32x4 sfr[2][4];
    __builtin_amdgcn_s_setprio(1);
#pragma unroll
    for (int qi = 0; qi < 2; ++qi)
#pragma unroll
      for (int kbl = 0; kbl < 4; ++kbl) {
        f32x4 a = f32x4{0.f, 0.f, 0.f, 0.f};
#pragma unroll
        for (int ks = 0; ks < 4; ++ks) {
          int key = kbl * 16 + lr;
          int byteoff = (key * 256 + (ks * 32 + lg * 8) * 2) ^ ((key & 7) << 4);
          s16x8 bfr = *(const s16x8*)((const char*)&Ks[b][0] + byteoff);
          a = __builtin_amdgcn_mfma_f32_16x16x32_bf16(qf[qi][ks], bfr, a, 0, 0, 0);
        }
        sfr[qi][kbl] = a;
      }
    __builtin_amdgcn_s_setprio(0);

    // no-max softmax: p = exp(bf16(bf16(s)*scale)); hand-rolled RNE (proven path)
#pragma unroll
    for (int qi = 0; qi < 2; ++qi)
#pragma unroll
      for (int kbl = 0; kbl < 4; ++kbl)
#pragma unroll
        for (int r = 0; r < 4; ++r) {
          float sv = bf16_to_f32(bf16_rne(sfr[qi][kbl][r])) * scale_bf;
          float p = __expf(bf16_to_f32(bf16_rne(sv)));
          Lp[qi][r] += p;
          int prow = qi * 16 + lg * 4 + r;
          Ps[w][prow * 64 + ((kbl * 16 + lr) ^ (((lg * 4 + r) & 7) << 3))] = bf16_rne(p);
        }

    asm volatile("s_waitcnt lgkmcnt(0)" ::: "memory");   // own-wave P writes visible

    s16x8 pa[2][2];
#pragma unroll
    for (int qi = 0; qi < 2; ++qi)
#pragma unroll
      for (int ks = 0; ks < 2; ++ks) {
        int prow = qi * 16 + lr;
        pa[qi][ks] = *(const s16x8*)&Ps[w][prow * 64 + ((ks * 32 + lg * 8) ^ ((lr & 7) << 3))];
      }
    __builtin_amdgcn_s_setprio(1);
#pragma unroll
    for (int db = 0; db < 8; ++db)
#pragma unroll
      for (int ks = 0; ks < 2; ++ks) {
        int d = db * 16 + lr;
        int byteoff = (d * 128 + (ks * 32 + lg * 8) * 2) ^ ((d & 7) << 4);
        s16x8 vb8 = *(const s16x8*)((const char*)&Vs[b][0] + byteoff);
        oacc[0][db] = __builtin_amdgcn_mfma_f32_16x16x32_bf16(pa[0][ks], vb8, oacc[0][db], 0, 0, 0);
        oacc[1][db] = __builtin_amdgcn_mfma_f32_16x16x32_bf16(pa[1][ks], vb8, oacc[1][db], 0, 0, 0);
      }
    __builtin_amdgcn_s_setprio(0);
    __syncthreads();
  }

  // deferred L reduction (once), then normalize + bf16 round + fp16-bit store
#pragma unroll
  for (int qi = 0; qi < 2; ++qi) {
    float rl[4];
#pragma unroll
    for (int r = 0; r < 4; ++r) {
      float s4 = Lp[qi][r];
#pragma unroll
      for (int m = 1; m < 16; m <<= 1) s4 += __shfl_xor(s4, m, 64);
      rl[r] = 1.0f / s4;
    }
#pragma unroll
    for (int db = 0; db < 8; ++db) {
      int d = db * 16 + lr;
#pragma unroll
      for (int r = 0; r < 4; ++r) {
        int q = qw0 + qi * 16 + lg * 4 + r;
        float obf16 = bf16_to_f32(bf16_rne(oacc[qi][db][r] * rl[r]));
        __half hh = __float2half(obf16);
        obf[(size_t)q * 2048 + h * 128 + d] = *(u16*)&hh;
      }
    }
  }
}

// ---------- launch ----------
extern "C" void kernel_launch(void* const* d_in, const int* in_sizes, int n_in,
                              void* d_out, int out_size, void* d_ws, size_t ws_size,
                              hipStream_t stream) {
  const float* x      = (const float*)d_in[0];
  const float* qkv_w  = (const float*)d_in[1];
  const float* qkv_b  = (const float*)d_in[2];
  const float* qnw    = (const float*)d_in[3];
  const float* knw    = (const float*)d_in[4];
  const float* proj_w = (const float*)d_in[5];
  const float* proj_b = (const float*)d_in[6];
  float* out = (float*)d_out;
  char* ws = (char*)d_ws;

  u16* xs    = (u16*)(ws + OFF_XSPLIT);
  u16* wsp   = (u16*)(ws + OFF_WSPLIT);
  u16* pwh   = (u16*)(ws + OFF_WSPLIT);   // fp16 proj_w, reuse after QKV GEMM
  float* qkf = (float*)(ws + OFF_QKF);
  u16* vb16  = (u16*)(ws + OFF_VB);
  u16* qb16  = (u16*)(ws + OFF_QB);
  u16* kb16  = (u16*)(ws + OFF_KB);
  u16* vt16  = (u16*)(ws + OFF_VT);
  u16* obf   = (u16*)(ws + OFF_XSPLIT);   // fp16 o, reuse (x splits dead after QKV GEMM)
  float* cosT = (float*)(ws + OFF_COS);
  float* sinT = (float*)(ws + OFF_SIN);

  u16* xsl = xs + (size_t)4096 * 2048;
  u16* wl  = wsp + (size_t)6144 * 2048;

  k_split<<<2048, 256, 0, stream>>>(x, xs, xsl, 4096 * 2048);
  k_split<<<2048, 256, 0, stream>>>(qkv_w, wsp, wl, 6144 * 2048);
  k_rope_table<<<1024, 256, 0, stream>>>(cosT, sinT);

  // QKV: fused 3-segment bf16 hi/lo
  k_gemm_qkv<<<dim3(48, 32), 256, 0, stream>>>(xs, xsl, wsp, wl, qkv_b, qkf, vb16);

  k_cvt16<<<2048, 256, 0, stream>>>(proj_w, pwh, 2048 * 2048 / 4);
  k_norm_rope<<<16384, 256, 0, stream>>>(qkf, qnw, knw, cosT, sinT, qb16, kb16);
  k_transpose_v<<<dim3(64, 16), 256, 0, stream>>>(vb16, vt16);
  k_attn<<<dim3(32, 16), 256, 0, stream>>>(qb16, kb16, vt16, obf);

  // proj: fp16 single segment
  k_gemm_proj<<<dim3(16, 32), 256, 0, stream>>>(obf, pwh, proj_b, out);
}

// Round 17
// 601.540 us; speedup vs baseline: 1.3246x; 1.0023x over previous
//
#include <hip/hip_runtime.h>
#include <hip/hip_bf16.h>
#include <hip/hip_fp16.h>

typedef unsigned short u16;
typedef unsigned int u32;
typedef __attribute__((ext_vector_type(8))) short s16x8;
typedef __attribute__((ext_vector_type(8))) _Float16 f16x8;
typedef __attribute__((ext_vector_type(4))) float f32x4;
typedef __attribute__((ext_vector_type(2))) float f32x2;
typedef __attribute__((ext_vector_type(4))) unsigned short u16x4;

#define DEV static __device__ __forceinline__

// ---------- helpers ----------
DEV u16 bf16_rne(float f) {
  u32 u = __float_as_uint(f);
  u32 r = 0x7FFFu + ((u >> 16) & 1u);
  return (u16)((u + r) >> 16);
}
DEV float bf16_to_f32(u16 h) { return __uint_as_float(((u32)h) << 16); }

typedef const __attribute__((address_space(1))) u32* gptr_t;
typedef __attribute__((address_space(3))) u32* lptr_t;
DEV void gload_lds16(const void* g, void* l) {
  __builtin_amdgcn_global_load_lds((gptr_t)g, (lptr_t)l, 16, 0, 0);
}

// ---------- workspace layout (bytes) ----------
#define OFF_XSPLIT  0ull                 // 2 * 4096*2048 u16 (Xh|Xl) ; reused as obf (fp16)
#define OFF_WSPLIT  33554432ull          // 2 * 6144*2048 u16 (Wh|Wl) ; reused as pwh (fp16)
#define OFF_QKF     83886080ull          // 4096*4096 f32 ([q|k] fp32)
#define OFF_VB      150994944ull         // v bf16 (n,h,d)
#define OFF_QB      167772160ull         // q bf16 (h,n,d)
#define OFF_KB      184549376ull         // k bf16 (h,n,d)
#define OFF_VT      201326592ull         // v bf16 (h,d,n)
#define OFF_COS     218103808ull
#define OFF_SIN     219152384ull

// ---------- fused prep: split x -> (Xh,Xl), split qkv_w -> (Wh,Wl), RoPE table. Vectorized. ----------
__global__ __launch_bounds__(256) void k_prep(
    const float* __restrict__ x,  u16* __restrict__ xh, u16* __restrict__ xl,
    const float* __restrict__ qw, u16* __restrict__ wh, u16* __restrict__ wl,
    float* __restrict__ cosT, float* __restrict__ sinT)
{
  const int tid0 = blockIdx.x * 256 + threadIdx.x;
  const int stride = gridDim.x * 256;

  // split x: 4096*2048 = 2,097,152 f32x4 chunks
  for (int i = tid0; i < 4096 * 2048 / 4; i += stride) {
    f32x4 v = *(const f32x4*)(x + (size_t)i * 4);
    u16x4 h4, l4;
#pragma unroll
    for (int j = 0; j < 4; ++j) {
      u16 h = bf16_rne(v[j]);
      h4[j] = h;
      l4[j] = bf16_rne(v[j] - bf16_to_f32(h));
    }
    *(u16x4*)(xh + (size_t)i * 4) = h4;
    *(u16x4*)(xl + (size_t)i * 4) = l4;
  }
  // split qkv_w: 6144*2048/4 = 3,145,728 chunks
  for (int i = tid0; i < 6144 * 2048 / 4; i += stride) {
    f32x4 v = *(const f32x4*)(qw + (size_t)i * 4);
    u16x4 h4, l4;
#pragma unroll
    for (int j = 0; j < 4; ++j) {
      u16 h = bf16_rne(v[j]);
      h4[j] = h;
      l4[j] = bf16_rne(v[j] - bf16_to_f32(h));
    }
    *(u16x4*)(wh + (size_t)i * 4) = h4;
    *(u16x4*)(wl + (size_t)i * 4) = l4;
  }
  // RoPE table: (n, 64)
  for (int i = tid0; i < 4096 * 64; i += stride) {
    int n = i >> 6, j = i & 63;
    int t = n >> 9, hh = (n >> 5) & 15, ww = n & 31;
    float pos, e;
    if (j < 32)      { pos = (float)t;  e = (float)j * (1.0f / 32.0f); }
    else if (j < 48) { pos = (float)hh; e = (float)(j - 32) * (1.0f / 16.0f); }
    else             { pos = (float)ww; e = (float)(j - 48) * (1.0f / 16.0f); }
    float inv = (float)pow(10000.0, -(double)e);
    float f = pos * inv;
    cosT[i] = cosf(f);
    sinT[i] = sinf(f);
  }
}

// ---------- fp32 -> fp16 convert (RNE) ----------
__global__ __launch_bounds__(256) void k_cvt16(const float* __restrict__ in,
                                               u16* __restrict__ out, int n4) {
  int i = blockIdx.x * 256 + threadIdx.x;
  int stride = gridDim.x * 256;
  for (; i < n4; i += stride) {
    f32x4 v = *(const f32x4*)(in + (size_t)i * 4);
    u16x4 o;
#pragma unroll
    for (int j = 0; j < 4; ++j) {
      __half h = __float2half(v[j]);
      o[j] = *(u16*)&h;
    }
    *(u16x4*)(out + (size_t)i * 4) = o;
  }
}

// ---------- QKV GEMM: fused 3-segment bf16 hi/lo, k-block unroll x2 (two buffer sets) ----------
// Identical addressing/swizzle per buffer as the proven r8-r16 kernel; barriers halved (32 rounds).
__global__ __launch_bounds__(256, 2) void k_gemm_qkv(
    const u16* __restrict__ Ah_, const u16* __restrict__ Al_,
    const u16* __restrict__ Bh_, const u16* __restrict__ Bl_,
    const float* __restrict__ bias,
    float* __restrict__ outF, u16* __restrict__ outV)
{
  __shared__ u16 AsH[2][128 * 32];
  __shared__ u16 AsL[2][128 * 32];
  __shared__ u16 BsH[2][128 * 32];
  __shared__ u16 BsL[2][128 * 32];
  const int t = threadIdx.x;
  const int lane = t & 63;
  const int lr = lane & 15, lg = lane >> 4;
  const int w = t >> 6;
  const int wr = w >> 1, wc = w & 1;
  const int row0 = blockIdx.y * 128;
  const int col0 = blockIdx.x * 128;
  const int K = 2048;

  f32x4 acc[4][4];
#pragma unroll
  for (int m = 0; m < 4; m++)
#pragma unroll
    for (int n = 0; n < 4; n++) acc[m][n] = f32x4{0.f, 0.f, 0.f, 0.f};

  const int c0 = t, c1 = t + 256;
  const int kp0 = ((c0 & 3) ^ ((c0 >> 3) & 3)) * 8;
  const int kp1 = ((c1 & 3) ^ ((c1 >> 3) & 3)) * 8;
  const int slot8 = (lg ^ ((lr >> 1) & 3)) * 8;
  const size_t ar0 = (size_t)(row0 + (c0 >> 2)) * K;
  const size_t ar1 = (size_t)(row0 + (c1 >> 2)) * K;
  const size_t br0 = (size_t)(col0 + (c0 >> 2)) * K;
  const size_t br1 = (size_t)(col0 + (c1 >> 2)) * K;

  for (int kb = 0; kb < 64; kb += 2) {
#pragma unroll
    for (int u = 0; u < 2; ++u) {
      const int k0 = (kb + u) * 32;
      gload_lds16(Ah_ + ar0 + k0 + kp0, &AsH[u][c0 * 8]);
      gload_lds16(Ah_ + ar1 + k0 + kp1, &AsH[u][c1 * 8]);
      gload_lds16(Al_ + ar0 + k0 + kp0, &AsL[u][c0 * 8]);
      gload_lds16(Al_ + ar1 + k0 + kp1, &AsL[u][c1 * 8]);
      gload_lds16(Bh_ + br0 + k0 + kp0, &BsH[u][c0 * 8]);
      gload_lds16(Bh_ + br1 + k0 + kp1, &BsH[u][c1 * 8]);
      gload_lds16(Bl_ + br0 + k0 + kp0, &BsL[u][c0 * 8]);
      gload_lds16(Bl_ + br1 + k0 + kp1, &BsL[u][c1 * 8]);
    }
    __syncthreads();
#pragma unroll
    for (int u = 0; u < 2; ++u) {
      s16x8 ah[4], al[4], bh[4], bl[4];
#pragma unroll
      for (int m = 0; m < 4; m++) {
        ah[m] = *(const s16x8*)&AsH[u][(wr * 64 + m * 16 + lr) * 32 + slot8];
        al[m] = *(const s16x8*)&AsL[u][(wr * 64 + m * 16 + lr) * 32 + slot8];
      }
#pragma unroll
      for (int n = 0; n < 4; n++) {
        bh[n] = *(const s16x8*)&BsH[u][(wc * 64 + n * 16 + lr) * 32 + slot8];
        bl[n] = *(const s16x8*)&BsL[u][(wc * 64 + n * 16 + lr) * 32 + slot8];
      }
      __builtin_amdgcn_s_setprio(1);
#pragma unroll
      for (int m = 0; m < 4; m++)
#pragma unroll
        for (int n = 0; n < 4; n++) {
          acc[m][n] = __builtin_amdgcn_mfma_f32_16x16x32_bf16(ah[m], bh[n], acc[m][n], 0, 0, 0);
          acc[m][n] = __builtin_amdgcn_mfma_f32_16x16x32_bf16(ah[m], bl[n], acc[m][n], 0, 0, 0);
          acc[m][n] = __builtin_amdgcn_mfma_f32_16x16x32_bf16(al[m], bh[n], acc[m][n], 0, 0, 0);
        }
      __builtin_amdgcn_s_setprio(0);
    }
    __syncthreads();
  }

#pragma unroll
  for (int m = 0; m < 4; m++) {
#pragma unroll
    for (int n = 0; n < 4; n++) {
      int col = col0 + wc * 64 + n * 16 + lr;
      float b = bias[col];
#pragma unroll
      for (int r = 0; r < 4; r++) {
        int row = row0 + wr * 64 + m * 16 + lg * 4 + r;
        float v = acc[m][n][r] + b;
        if (col < 4096) outF[(size_t)row * 4096 + col] = v;
        else            outV[(size_t)row * 2048 + (col - 4096)] = bf16_rne(v);
      }
    }
  }
}

// ---------- proj GEMM: fp16 single segment (o is bf16-exact in fp16; only w rounded) ----------
__global__ __launch_bounds__(256, 2) void k_gemm_proj(
    const u16* __restrict__ A, const u16* __restrict__ B,
    const float* __restrict__ bias, float* __restrict__ outF)
{
  __shared__ u16 As[128 * 32];
  __shared__ u16 Bs[128 * 32];
  const int t = threadIdx.x;
  const int lane = t & 63;
  const int lr = lane & 15, lg = lane >> 4;
  const int w = t >> 6;
  const int wr = w >> 1, wc = w & 1;
  const int row0 = blockIdx.y * 128;
  const int col0 = blockIdx.x * 128;
  const int K = 2048;

  f32x4 acc[4][4];
#pragma unroll
  for (int m = 0; m < 4; m++)
#pragma unroll
    for (int n = 0; n < 4; n++) acc[m][n] = f32x4{0.f, 0.f, 0.f, 0.f};

  const int c0 = t, c1 = t + 256;
  const int kp0 = ((c0 & 3) ^ ((c0 >> 3) & 3)) * 8;
  const int kp1 = ((c1 & 3) ^ ((c1 >> 3) & 3)) * 8;
  const int slot8 = (lg ^ ((lr >> 1) & 3)) * 8;

  for (int kb = 0; kb < 64; ++kb) {
    const int k0 = kb * 32;
    gload_lds16(A + (size_t)(row0 + (c0 >> 2)) * K + k0 + kp0, &As[c0 * 8]);
    gload_lds16(A + (size_t)(row0 + (c1 >> 2)) * K + k0 + kp1, &As[c1 * 8]);
    gload_lds16(B + (size_t)(col0 + (c0 >> 2)) * K + k0 + kp0, &Bs[c0 * 8]);
    gload_lds16(B + (size_t)(col0 + (c1 >> 2)) * K + k0 + kp1, &Bs[c1 * 8]);
    __syncthreads();
    f16x8 af[4], bf[4];
#pragma unroll
    for (int m = 0; m < 4; m++)
      af[m] = *(const f16x8*)&As[(wr * 64 + m * 16 + lr) * 32 + slot8];
#pragma unroll
    for (int n = 0; n < 4; n++)
      bf[n] = *(const f16x8*)&Bs[(wc * 64 + n * 16 + lr) * 32 + slot8];
    __builtin_amdgcn_s_setprio(1);
#pragma unroll
    for (int m = 0; m < 4; m++)
#pragma unroll
      for (int n = 0; n < 4; n++)
        acc[m][n] = __builtin_amdgcn_mfma_f32_16x16x32_f16(af[m], bf[n], acc[m][n], 0, 0, 0);
    __builtin_amdgcn_s_setprio(0);
    __syncthreads();
  }

#pragma unroll
  for (int m = 0; m < 4; m++) {
#pragma unroll
    for (int n = 0; n < 4; n++) {
      int col = col0 + wc * 64 + n * 16 + lr;
      float b = bias[col];
#pragma unroll
      for (int r = 0; r < 4; r++) {
        int row = row0 + wr * 64 + m * 16 + lg * 4 + r;
        outF[(size_t)row * 2048 + col] = acc[m][n][r] + b;
      }
    }
  }
}

// ---------- RMSNorm (fp32) + RoPE + bf16 cast for q,k. One wave per (n,h). ----------
__global__ __launch_bounds__(256) void k_norm_rope(
    const float* __restrict__ qkf, const float* __restrict__ qw, const float* __restrict__ kw,
    const float* __restrict__ cosT, const float* __restrict__ sinT,
    u16* __restrict__ qb, u16* __restrict__ kb)
{
  int gw = (blockIdx.x * 256 + threadIdx.x) >> 6;
  int lane = threadIdx.x & 63;
  int n = gw >> 4;
  int h = gw & 15;
  float c = cosT[n * 64 + lane];
  float s = sinT[n * 64 + lane];
#pragma unroll
  for (int p = 0; p < 2; ++p) {
    const float* src = qkf + (size_t)n * 4096 + p * 2048 + h * 128;
    f32x2 xv = *(const f32x2*)(src + lane * 2);
    float xr = xv[0], xi = xv[1];
    float ss = xr * xr + xi * xi;
#pragma unroll
    for (int m = 1; m < 64; m <<= 1) ss += __shfl_xor(ss, m, 64);
    float r = 1.0f / sqrtf(ss * (1.0f / 128.0f) + 1e-6f);
    const float* wgt = p ? kw : qw;
    float yr = xr * r * wgt[lane * 2];
    float yi = xi * r * wgt[lane * 2 + 1];
    float o0 = yr * c - yi * s;
    float o1 = yr * s + yi * c;
    u16* dst = (p ? kb : qb) + (size_t)h * 4096 * 128 + (size_t)n * 128 + lane * 2;
    *(u32*)dst = ((u32)bf16_rne(o1) << 16) | bf16_rne(o0);
  }
}

// ---------- V transpose: (n, h*128+d) -> (h, d, n) ----------
__global__ __launch_bounds__(256) void k_transpose_v(const u16* __restrict__ vb, u16* __restrict__ vt) {
  __shared__ u16 Vs[64][136];
  int h = blockIdx.y;
  int n0 = blockIdx.x * 64;
  int t = threadIdx.x;
  int nl = t >> 2, d0 = (t & 3) * 32;
  const u16* src = vb + (size_t)(n0 + nl) * 2048 + h * 128 + d0;
#pragma unroll
  for (int i = 0; i < 8; ++i)
    *(u16x4*)&Vs[nl][d0 + i * 4] = *(const u16x4*)(src + i * 4);
  __syncthreads();
  int d = t >> 1, nc = (t & 1) * 32;
  u16* dst = vt + (size_t)h * 128 * 4096 + (size_t)d * 4096 + n0 + nc;
#pragma unroll
  for (int j4 = 0; j4 < 8; ++j4) {
    u16x4 o;
    o.x = Vs[nc + j4 * 4 + 0][d];
    o.y = Vs[nc + j4 * 4 + 1][d];
    o.z = Vs[nc + j4 * 4 + 2][d];
    o.w = Vs[nc + j4 * 4 + 3][d];
    *(u16x4*)(dst + j4 * 4) = o;
  }
}

// ---------- flash attention: r16 proven kernel (no-max softmax, deferred L) ----------
__global__ __launch_bounds__(256, 2) void k_attn(
    const u16* __restrict__ qb, const u16* __restrict__ kb, const u16* __restrict__ vt,
    u16* __restrict__ obf)
{
  __shared__ u16 Ks[2][64 * 128];
  __shared__ u16 Vs[2][128 * 64];
  __shared__ u16 Ps[4][32 * 64];
  const int t = threadIdx.x;
  const int lane = t & 63;
  const int lr = lane & 15, lg = lane >> 4;
  const int w = t >> 6;

  const int bid = blockIdx.y * 32 + blockIdx.x;
  const int h = (bid & 7) + 8 * ((bid >> 3) >> 5);
  const int qt = (bid >> 3) & 31;
  const int qw0 = qt * 128 + w * 32;

  const u16* qh = qb + (size_t)h * 4096 * 128;
  const u16* kh = kb + (size_t)h * 4096 * 128;
  const u16* vh = vt + (size_t)h * 128 * 4096;

  s16x8 qf[2][4];
#pragma unroll
  for (int qi = 0; qi < 2; ++qi)
#pragma unroll
    for (int ks = 0; ks < 4; ++ks)
      qf[qi][ks] = *(const s16x8*)(qh + (size_t)(qw0 + qi * 16 + lr) * 128 + ks * 32 + lg * 8);

  f32x4 oacc[2][8];
#pragma unroll
  for (int i = 0; i < 2; i++)
#pragma unroll
    for (int j = 0; j < 8; j++) oacc[i][j] = f32x4{0.f, 0.f, 0.f, 0.f};
  float Lp[2][4];
#pragma unroll
  for (int i = 0; i < 2; i++)
#pragma unroll
    for (int r = 0; r < 4; r++) Lp[i][r] = 0.f;

  const float scale_bf = bf16_to_f32(bf16_rne(0.08838834764831845f));

  auto stageKV = [&](int kt, int b) __attribute__((always_inline)) {
#pragma unroll
    for (int i = 0; i < 4; ++i) {
      int c = t + i * 256;
      int row = c >> 4;
      int cc = (c & 15) ^ (row & 7);
      gload_lds16(kh + (size_t)(kt * 64 + row) * 128 + cc * 8, &Ks[b][c * 8]);
    }
#pragma unroll
    for (int i = 0; i < 4; ++i) {
      int c = t + i * 256;
      int d = c >> 3;
      int cc = (c & 7) ^ (d & 7);
      gload_lds16(vh + (size_t)d * 4096 + kt * 64 + cc * 8, &Vs[b][c * 8]);
    }
  };

  stageKV(0, 0);
  __syncthreads();

  for (int kt = 0; kt < 64; ++kt) {
    const int b = kt & 1;
    if (kt + 1 < 64) stageKV(kt + 1, b ^ 1);

    f32x4 sfr[2][4];
    __builtin_amdgcn_s_setprio(1);
#pragma unroll
    for (int qi = 0; qi < 2; ++qi)
#pragma unroll
      for (int kbl = 0; kbl < 4; ++kbl) {
        f32x4 a = f32x4{0.f, 0.f, 0.f, 0.f};
#pragma unroll
        for (int ks = 0; ks < 4; ++ks) {
          int key = kbl * 16 + lr;
          int byteoff = (key * 256 + (ks * 32 + lg * 8) * 2) ^ ((key & 7) << 4);
          s16x8 bfr = *(const s16x8*)((const char*)&Ks[b][0] + byteoff);
          a = __builtin_amdgcn_mfma_f32_16x16x32_bf16(qf[qi][ks], bfr, a, 0, 0, 0);
        }
        sfr[qi][kbl] = a;
      }
    __builtin_amdgcn_s_setprio(0);

    // no-max softmax: p = exp(bf16(bf16(s)*scale)); hand-rolled RNE (proven path)
#pragma unroll
    for (int qi = 0; qi < 2; ++qi)
#pragma unroll
      for (int kbl = 0; kbl < 4; ++kbl)
#pragma unroll
        for (int r = 0; r < 4; ++r) {
          float sv = bf16_to_f32(bf16_rne(sfr[qi][kbl][r])) * scale_bf;
          float p = __expf(bf16_to_f32(bf16_rne(sv)));
          Lp[qi][r] += p;
          int prow = qi * 16 + lg * 4 + r;
          Ps[w][prow * 64 + ((kbl * 16 + lr) ^ (((lg * 4 + r) & 7) << 3))] = bf16_rne(p);
        }

    asm volatile("s_waitcnt lgkmcnt(0)" ::: "memory");   // own-wave P writes visible

    s16x8 pa[2][2];
#pragma unroll
    for (int qi = 0; qi < 2; ++qi)
#pragma unroll
      for (int ks = 0; ks < 2; ++ks) {
        int prow = qi * 16 + lr;
        pa[qi][ks] = *(const s16x8*)&Ps[w][prow * 64 + ((ks * 32 + lg * 8) ^ ((lr & 7) << 3))];
      }
    __builtin_amdgcn_s_setprio(1);
#pragma unroll
    for (int db = 0; db < 8; ++db)
#pragma unroll
      for (int ks = 0; ks < 2; ++ks) {
        int d = db * 16 + lr;
        int byteoff = (d * 128 + (ks * 32 + lg * 8) * 2) ^ ((d & 7) << 4);
        s16x8 vb8 = *(const s16x8*)((const char*)&Vs[b][0] + byteoff);
        oacc[0][db] = __builtin_amdgcn_mfma_f32_16x16x32_bf16(pa[0][ks], vb8, oacc[0][db], 0, 0, 0);
        oacc[1][db] = __builtin_amdgcn_mfma_f32_16x16x32_bf16(pa[1][ks], vb8, oacc[1][db], 0, 0, 0);
      }
    __builtin_amdgcn_s_setprio(0);
    __syncthreads();
  }

  // deferred L reduction (once), then normalize + bf16 round + fp16-bit store
#pragma unroll
  for (int qi = 0; qi < 2; ++qi) {
    float rl[4];
#pragma unroll
    for (int r = 0; r < 4; ++r) {
      float s4 = Lp[qi][r];
#pragma unroll
      for (int m = 1; m < 16; m <<= 1) s4 += __shfl_xor(s4, m, 64);
      rl[r] = 1.0f / s4;
    }
#pragma unroll
    for (int db = 0; db < 8; ++db) {
      int d = db * 16 + lr;
#pragma unroll
      for (int r = 0; r < 4; ++r) {
        int q = qw0 + qi * 16 + lg * 4 + r;
        float obf16 = bf16_to_f32(bf16_rne(oacc[qi][db][r] * rl[r]));
        __half hh = __float2half(obf16);
        obf[(size_t)q * 2048 + h * 128 + d] = *(u16*)&hh;
      }
    }
  }
}

// ---------- launch ----------
extern "C" void kernel_launch(void* const* d_in, const int* in_sizes, int n_in,
                              void* d_out, int out_size, void* d_ws, size_t ws_size,
                              hipStream_t stream) {
  const float* x      = (const float*)d_in[0];
  const float* qkv_w  = (const float*)d_in[1];
  const float* qkv_b  = (const float*)d_in[2];
  const float* qnw    = (const float*)d_in[3];
  const float* knw    = (const float*)d_in[4];
  const float* proj_w = (const float*)d_in[5];
  const float* proj_b = (const float*)d_in[6];
  float* out = (float*)d_out;
  char* ws = (char*)d_ws;

  u16* xs    = (u16*)(ws + OFF_XSPLIT);
  u16* wsp   = (u16*)(ws + OFF_WSPLIT);
  u16* pwh   = (u16*)(ws + OFF_WSPLIT);   // fp16 proj_w, reuse after QKV GEMM
  float* qkf = (float*)(ws + OFF_QKF);
  u16* vb16  = (u16*)(ws + OFF_VB);
  u16* qb16  = (u16*)(ws + OFF_QB);
  u16* kb16  = (u16*)(ws + OFF_KB);
  u16* vt16  = (u16*)(ws + OFF_VT);
  u16* obf   = (u16*)(ws + OFF_XSPLIT);   // fp16 o, reuse (x splits dead after QKV GEMM)
  float* cosT = (float*)(ws + OFF_COS);
  float* sinT = (float*)(ws + OFF_SIN);

  u16* xsl = xs + (size_t)4096 * 2048;
  u16* wl  = wsp + (size_t)6144 * 2048;

  // fused prep (vectorized): x split + w split + rope table
  k_prep<<<2048, 256, 0, stream>>>(x, xs, xsl, qkv_w, wsp, wl, cosT, sinT);

  // QKV: fused 3-segment bf16 hi/lo, k-unroll x2
  k_gemm_qkv<<<dim3(48, 32), 256, 0, stream>>>(xs, xsl, wsp, wl, qkv_b, qkf, vb16);

  k_cvt16<<<2048, 256, 0, stream>>>(proj_w, pwh, 2048 * 2048 / 4);
  k_norm_rope<<<16384, 256, 0, stream>>>(qkf, qnw, knw, cosT, sinT, qb16, kb16);
  k_transpose_v<<<dim3(64, 16), 256, 0, stream>>>(vb16, vt16);
  k_attn<<<dim3(32, 16), 256, 0, stream>>>(qb16, kb16, vt16, obf);

  // proj: fp16 single segment
  k_gemm_proj<<<dim3(16, 32), 256, 0, stream>>>(obf, pwh, proj_b, out);
}

// Round 18
// 445.865 us; speedup vs baseline: 1.7871x; 1.3492x over previous
//
#include <hip/hip_runtime.h>
#include <hip/hip_bf16.h>
#include <hip/hip_fp16.h>

typedef unsigned short u16;
typedef unsigned int u32;
typedef __attribute__((ext_vector_type(8))) short s16x8;
typedef __attribute__((ext_vector_type(8))) _Float16 f16x8;
typedef __attribute__((ext_vector_type(4))) float f32x4;
typedef __attribute__((ext_vector_type(2))) float f32x2;
typedef __attribute__((ext_vector_type(4))) unsigned short u16x4;

#define DEV static __device__ __forceinline__

// ---------- helpers ----------
DEV u16 bf16_rne(float f) {
  u32 u = __float_as_uint(f);
  u32 r = 0x7FFFu + ((u >> 16) & 1u);
  return (u16)((u + r) >> 16);
}
DEV float bf16_to_f32(u16 h) { return __uint_as_float(((u32)h) << 16); }

typedef const __attribute__((address_space(1))) u32* gptr_t;
typedef __attribute__((address_space(3))) u32* lptr_t;
DEV void gload_lds16(const void* g, void* l) {
  __builtin_amdgcn_global_load_lds((gptr_t)g, (lptr_t)l, 16, 0, 0);
}

// ---------- workspace layout (bytes) ----------
#define OFF_XSPLIT  0ull                 // fp16 x (16.8 MB) ; reused as obf (fp16)
#define OFF_WSPLIT  33554432ull          // fp16 qkv_w (25.2 MB) ; reused as pwh (fp16)
#define OFF_QKF     83886080ull          // 4096*4096 f32 ([q|k] fp32)
#define OFF_VB      150994944ull         // v bf16 (n,h,d)
#define OFF_QB      167772160ull         // q bf16 (h,n,d)
#define OFF_KB      184549376ull         // k bf16 (h,n,d)
#define OFF_VT      201326592ull         // v bf16 (h,d,n)
#define OFF_COS     218103808ull
#define OFF_SIN     219152384ull

// ---------- fused prep: x -> fp16, qkv_w -> fp16, RoPE table. Vectorized. ----------
__global__ __launch_bounds__(256) void k_prep(
    const float* __restrict__ x,  u16* __restrict__ xh,
    const float* __restrict__ qw, u16* __restrict__ wh,
    float* __restrict__ cosT, float* __restrict__ sinT)
{
  const int tid0 = blockIdx.x * 256 + threadIdx.x;
  const int stride = gridDim.x * 256;

  for (int i = tid0; i < 4096 * 2048 / 4; i += stride) {
    f32x4 v = *(const f32x4*)(x + (size_t)i * 4);
    u16x4 o;
#pragma unroll
    for (int j = 0; j < 4; ++j) {
      __half h = __float2half(v[j]);
      o[j] = *(u16*)&h;
    }
    *(u16x4*)(xh + (size_t)i * 4) = o;
  }
  for (int i = tid0; i < 6144 * 2048 / 4; i += stride) {
    f32x4 v = *(const f32x4*)(qw + (size_t)i * 4);
    u16x4 o;
#pragma unroll
    for (int j = 0; j < 4; ++j) {
      __half h = __float2half(v[j]);
      o[j] = *(u16*)&h;
    }
    *(u16x4*)(wh + (size_t)i * 4) = o;
  }
  for (int i = tid0; i < 4096 * 64; i += stride) {
    int n = i >> 6, j = i & 63;
    int t = n >> 9, hh = (n >> 5) & 15, ww = n & 31;
    float pos, e;
    if (j < 32)      { pos = (float)t;  e = (float)j * (1.0f / 32.0f); }
    else if (j < 48) { pos = (float)hh; e = (float)(j - 32) * (1.0f / 16.0f); }
    else             { pos = (float)ww; e = (float)(j - 48) * (1.0f / 16.0f); }
    float inv = (float)pow(10000.0, -(double)e);
    float f = pos * inv;
    cosT[i] = cosf(f);
    sinT[i] = sinf(f);
  }
}

// ---------- fp32 -> fp16 convert (RNE) ----------
__global__ __launch_bounds__(256) void k_cvt16(const float* __restrict__ in,
                                               u16* __restrict__ out, int n4) {
  int i = blockIdx.x * 256 + threadIdx.x;
  int stride = gridDim.x * 256;
  for (; i < n4; i += stride) {
    f32x4 v = *(const f32x4*)(in + (size_t)i * 4);
    u16x4 o;
#pragma unroll
    for (int j = 0; j < 4; ++j) {
      __half h = __float2half(v[j]);
      o[j] = *(u16*)&h;
    }
    *(u16x4*)(out + (size_t)i * 4) = o;
  }
}

// ---------- QKV GEMM: single-segment fp16 (proven proj structure + MODE-0 epilogue) ----------
__global__ __launch_bounds__(256, 2) void k_gemm_qkv16(
    const u16* __restrict__ A, const u16* __restrict__ B,
    const float* __restrict__ bias,
    float* __restrict__ outF, u16* __restrict__ outV)
{
  __shared__ u16 As[128 * 32];
  __shared__ u16 Bs[128 * 32];
  const int t = threadIdx.x;
  const int lane = t & 63;
  const int lr = lane & 15, lg = lane >> 4;
  const int w = t >> 6;
  const int wr = w >> 1, wc = w & 1;
  const int row0 = blockIdx.y * 128;
  const int col0 = blockIdx.x * 128;
  const int K = 2048;

  f32x4 acc[4][4];
#pragma unroll
  for (int m = 0; m < 4; m++)
#pragma unroll
    for (int n = 0; n < 4; n++) acc[m][n] = f32x4{0.f, 0.f, 0.f, 0.f};

  const int c0 = t, c1 = t + 256;
  const int kp0 = ((c0 & 3) ^ ((c0 >> 3) & 3)) * 8;
  const int kp1 = ((c1 & 3) ^ ((c1 >> 3) & 3)) * 8;
  const int slot8 = (lg ^ ((lr >> 1) & 3)) * 8;

  for (int kb = 0; kb < 64; ++kb) {
    const int k0 = kb * 32;
    gload_lds16(A + (size_t)(row0 + (c0 >> 2)) * K + k0 + kp0, &As[c0 * 8]);
    gload_lds16(A + (size_t)(row0 + (c1 >> 2)) * K + k0 + kp1, &As[c1 * 8]);
    gload_lds16(B + (size_t)(col0 + (c0 >> 2)) * K + k0 + kp0, &Bs[c0 * 8]);
    gload_lds16(B + (size_t)(col0 + (c1 >> 2)) * K + k0 + kp1, &Bs[c1 * 8]);
    __syncthreads();
    f16x8 af[4], bf[4];
#pragma unroll
    for (int m = 0; m < 4; m++)
      af[m] = *(const f16x8*)&As[(wr * 64 + m * 16 + lr) * 32 + slot8];
#pragma unroll
    for (int n = 0; n < 4; n++)
      bf[n] = *(const f16x8*)&Bs[(wc * 64 + n * 16 + lr) * 32 + slot8];
    __builtin_amdgcn_s_setprio(1);
#pragma unroll
    for (int m = 0; m < 4; m++)
#pragma unroll
      for (int n = 0; n < 4; n++)
        acc[m][n] = __builtin_amdgcn_mfma_f32_16x16x32_f16(af[m], bf[n], acc[m][n], 0, 0, 0);
    __builtin_amdgcn_s_setprio(0);
    __syncthreads();
  }

#pragma unroll
  for (int m = 0; m < 4; m++) {
#pragma unroll
    for (int n = 0; n < 4; n++) {
      int col = col0 + wc * 64 + n * 16 + lr;
      float b = bias[col];
#pragma unroll
      for (int r = 0; r < 4; r++) {
        int row = row0 + wr * 64 + m * 16 + lg * 4 + r;
        float v = acc[m][n][r] + b;
        if (col < 4096) outF[(size_t)row * 4096 + col] = v;
        else            outV[(size_t)row * 2048 + (col - 4096)] = bf16_rne(v);
      }
    }
  }
}

// ---------- proj GEMM: fp16 single segment ----------
__global__ __launch_bounds__(256, 2) void k_gemm_proj(
    const u16* __restrict__ A, const u16* __restrict__ B,
    const float* __restrict__ bias, float* __restrict__ outF)
{
  __shared__ u16 As[128 * 32];
  __shared__ u16 Bs[128 * 32];
  const int t = threadIdx.x;
  const int lane = t & 63;
  const int lr = lane & 15, lg = lane >> 4;
  const int w = t >> 6;
  const int wr = w >> 1, wc = w & 1;
  const int row0 = blockIdx.y * 128;
  const int col0 = blockIdx.x * 128;
  const int K = 2048;

  f32x4 acc[4][4];
#pragma unroll
  for (int m = 0; m < 4; m++)
#pragma unroll
    for (int n = 0; n < 4; n++) acc[m][n] = f32x4{0.f, 0.f, 0.f, 0.f};

  const int c0 = t, c1 = t + 256;
  const int kp0 = ((c0 & 3) ^ ((c0 >> 3) & 3)) * 8;
  const int kp1 = ((c1 & 3) ^ ((c1 >> 3) & 3)) * 8;
  const int slot8 = (lg ^ ((lr >> 1) & 3)) * 8;

  for (int kb = 0; kb < 64; ++kb) {
    const int k0 = kb * 32;
    gload_lds16(A + (size_t)(row0 + (c0 >> 2)) * K + k0 + kp0, &As[c0 * 8]);
    gload_lds16(A + (size_t)(row0 + (c1 >> 2)) * K + k0 + kp1, &As[c1 * 8]);
    gload_lds16(B + (size_t)(col0 + (c0 >> 2)) * K + k0 + kp0, &Bs[c0 * 8]);
    gload_lds16(B + (size_t)(col0 + (c1 >> 2)) * K + k0 + kp1, &Bs[c1 * 8]);
    __syncthreads();
    f16x8 af[4], bf[4];
#pragma unroll
    for (int m = 0; m < 4; m++)
      af[m] = *(const f16x8*)&As[(wr * 64 + m * 16 + lr) * 32 + slot8];
#pragma unroll
    for (int n = 0; n < 4; n++)
      bf[n] = *(const f16x8*)&Bs[(wc * 64 + n * 16 + lr) * 32 + slot8];
    __builtin_amdgcn_s_setprio(1);
#pragma unroll
    for (int m = 0; m < 4; m++)
#pragma unroll
      for (int n = 0; n < 4; n++)
        acc[m][n] = __builtin_amdgcn_mfma_f32_16x16x32_f16(af[m], bf[n], acc[m][n], 0, 0, 0);
    __builtin_amdgcn_s_setprio(0);
    __syncthreads();
  }

#pragma unroll
  for (int m = 0; m < 4; m++) {
#pragma unroll
    for (int n = 0; n < 4; n++) {
      int col = col0 + wc * 64 + n * 16 + lr;
      float b = bias[col];
#pragma unroll
      for (int r = 0; r < 4; r++) {
        int row = row0 + wr * 64 + m * 16 + lg * 4 + r;
        outF[(size_t)row * 2048 + col] = acc[m][n][r] + b;
      }
    }
  }
}

// ---------- RMSNorm (fp32) + RoPE + bf16 cast for q,k. One wave per (n,h). ----------
__global__ __launch_bounds__(256) void k_norm_rope(
    const float* __restrict__ qkf, const float* __restrict__ qw, const float* __restrict__ kw,
    const float* __restrict__ cosT, const float* __restrict__ sinT,
    u16* __restrict__ qb, u16* __restrict__ kb)
{
  int gw = (blockIdx.x * 256 + threadIdx.x) >> 6;
  int lane = threadIdx.x & 63;
  int n = gw >> 4;
  int h = gw & 15;
  float c = cosT[n * 64 + lane];
  float s = sinT[n * 64 + lane];
#pragma unroll
  for (int p = 0; p < 2; ++p) {
    const float* src = qkf + (size_t)n * 4096 + p * 2048 + h * 128;
    f32x2 xv = *(const f32x2*)(src + lane * 2);
    float xr = xv[0], xi = xv[1];
    float ss = xr * xr + xi * xi;
#pragma unroll
    for (int m = 1; m < 64; m <<= 1) ss += __shfl_xor(ss, m, 64);
    float r = 1.0f / sqrtf(ss * (1.0f / 128.0f) + 1e-6f);
    const float* wgt = p ? kw : qw;
    float yr = xr * r * wgt[lane * 2];
    float yi = xi * r * wgt[lane * 2 + 1];
    float o0 = yr * c - yi * s;
    float o1 = yr * s + yi * c;
    u16* dst = (p ? kb : qb) + (size_t)h * 4096 * 128 + (size_t)n * 128 + lane * 2;
    *(u32*)dst = ((u32)bf16_rne(o1) << 16) | bf16_rne(o0);
  }
}

// ---------- V transpose: (n, h*128+d) -> (h, d, n) ----------
__global__ __launch_bounds__(256) void k_transpose_v(const u16* __restrict__ vb, u16* __restrict__ vt) {
  __shared__ u16 Vs[64][136];
  int h = blockIdx.y;
  int n0 = blockIdx.x * 64;
  int t = threadIdx.x;
  int nl = t >> 2, d0 = (t & 3) * 32;
  const u16* src = vb + (size_t)(n0 + nl) * 2048 + h * 128 + d0;
#pragma unroll
  for (int i = 0; i < 8; ++i)
    *(u16x4*)&Vs[nl][d0 + i * 4] = *(const u16x4*)(src + i * 4);
  __syncthreads();
  int d = t >> 1, nc = (t & 1) * 32;
  u16* dst = vt + (size_t)h * 128 * 4096 + (size_t)d * 4096 + n0 + nc;
#pragma unroll
  for (int j4 = 0; j4 < 8; ++j4) {
    u16x4 o;
    o.x = Vs[nc + j4 * 4 + 0][d];
    o.y = Vs[nc + j4 * 4 + 1][d];
    o.z = Vs[nc + j4 * 4 + 2][d];
    o.w = Vs[nc + j4 * 4 + 3][d];
    *(u16x4*)(dst + j4 * 4) = o;
  }
}

// ---------- flash attention: r16 proven kernel (no-max softmax, deferred L) ----------
__global__ __launch_bounds__(256, 2) void k_attn(
    const u16* __restrict__ qb, const u16* __restrict__ kb, const u16* __restrict__ vt,
    u16* __restrict__ obf)
{
  __shared__ u16 Ks[2][64 * 128];
  __shared__ u16 Vs[2][128 * 64];
  __shared__ u16 Ps[4][32 * 64];
  const int t = threadIdx.x;
  const int lane = t & 63;
  const int lr = lane & 15, lg = lane >> 4;
  const int w = t >> 6;

  const int bid = blockIdx.y * 32 + blockIdx.x;
  const int h = (bid & 7) + 8 * ((bid >> 3) >> 5);
  const int qt = (bid >> 3) & 31;
  const int qw0 = qt * 128 + w * 32;

  const u16* qh = qb + (size_t)h * 4096 * 128;
  const u16* kh = kb + (size_t)h * 4096 * 128;
  const u16* vh = vt + (size_t)h * 128 * 4096;

  s16x8 qf[2][4];
#pragma unroll
  for (int qi = 0; qi < 2; ++qi)
#pragma unroll
    for (int ks = 0; ks < 4; ++ks)
      qf[qi][ks] = *(const s16x8*)(qh + (size_t)(qw0 + qi * 16 + lr) * 128 + ks * 32 + lg * 8);

  f32x4 oacc[2][8];
#pragma unroll
  for (int i = 0; i < 2; i++)
#pragma unroll
    for (int j = 0; j < 8; j++) oacc[i][j] = f32x4{0.f, 0.f, 0.f, 0.f};
  float Lp[2][4];
#pragma unroll
  for (int i = 0; i < 2; i++)
#pragma unroll
    for (int r = 0; r < 4; r++) Lp[i][r] = 0.f;

  const float scale_bf = bf16_to_f32(bf16_rne(0.08838834764831845f));

  auto stageKV = [&](int kt, int b) __attribute__((always_inline)) {
#pragma unroll
    for (int i = 0; i < 4; ++i) {
      int c = t + i * 256;
      int row = c >> 4;
      int cc = (c & 15) ^ (row & 7);
      gload_lds16(kh + (size_t)(kt * 64 + row) * 128 + cc * 8, &Ks[b][c * 8]);
    }
#pragma unroll
    for (int i = 0; i < 4; ++i) {
      int c = t + i * 256;
      int d = c >> 3;
      int cc = (c & 7) ^ (d & 7);
      gload_lds16(vh + (size_t)d * 4096 + kt * 64 + cc * 8, &Vs[b][c * 8]);
    }
  };

  stageKV(0, 0);
  __syncthreads();

  for (int kt = 0; kt < 64; ++kt) {
    const int b = kt & 1;
    if (kt + 1 < 64) stageKV(kt + 1, b ^ 1);

    f32x4 sfr[2][4];
    __builtin_amdgcn_s_setprio(1);
#pragma unroll
    for (int qi = 0; qi < 2; ++qi)
#pragma unroll
      for (int kbl = 0; kbl < 4; ++kbl) {
        f32x4 a = f32x4{0.f, 0.f, 0.f, 0.f};
#pragma unroll
        for (int ks = 0; ks < 4; ++ks) {
          int key = kbl * 16 + lr;
          int byteoff = (key * 256 + (ks * 32 + lg * 8) * 2) ^ ((key & 7) << 4);
          s16x8 bfr = *(const s16x8*)((const char*)&Ks[b][0] + byteoff);
          a = __builtin_amdgcn_mfma_f32_16x16x32_bf16(qf[qi][ks], bfr, a, 0, 0, 0);
        }
        sfr[qi][kbl] = a;
      }
    __builtin_amdgcn_s_setprio(0);

    // no-max softmax: p = exp(bf16(bf16(s)*scale)); hand-rolled RNE (proven path)
#pragma unroll
    for (int qi = 0; qi < 2; ++qi)
#pragma unroll
      for (int kbl = 0; kbl < 4; ++kbl)
#pragma unroll
        for (int r = 0; r < 4; ++r) {
          float sv = bf16_to_f32(bf16_rne(sfr[qi][kbl][r])) * scale_bf;
          float p = __expf(bf16_to_f32(bf16_rne(sv)));
          Lp[qi][r] += p;
          int prow = qi * 16 + lg * 4 + r;
          Ps[w][prow * 64 + ((kbl * 16 + lr) ^ (((lg * 4 + r) & 7) << 3))] = bf16_rne(p);
        }

    asm volatile("s_waitcnt lgkmcnt(0)" ::: "memory");   // own-wave P writes visible

    s16x8 pa[2][2];
#pragma unroll
    for (int qi = 0; qi < 2; ++qi)
#pragma unroll
      for (int ks = 0; ks < 2; ++ks) {
        int prow = qi * 16 + lr;
        pa[qi][ks] = *(const s16x8*)&Ps[w][prow * 64 + ((ks * 32 + lg * 8) ^ ((lr & 7) << 3))];
      }
    __builtin_amdgcn_s_setprio(1);
#pragma unroll
    for (int db = 0; db < 8; ++db)
#pragma unroll
      for (int ks = 0; ks < 2; ++ks) {
        int d = db * 16 + lr;
        int byteoff = (d * 128 + (ks * 32 + lg * 8) * 2) ^ ((d & 7) << 4);
        s16x8 vb8 = *(const s16x8*)((const char*)&Vs[b][0] + byteoff);
        oacc[0][db] = __builtin_amdgcn_mfma_f32_16x16x32_bf16(pa[0][ks], vb8, oacc[0][db], 0, 0, 0);
        oacc[1][db] = __builtin_amdgcn_mfma_f32_16x16x32_bf16(pa[1][ks], vb8, oacc[1][db], 0, 0, 0);
      }
    __builtin_amdgcn_s_setprio(0);
    __syncthreads();
  }

  // deferred L reduction (once), then normalize + bf16 round + fp16-bit store
#pragma unroll
  for (int qi = 0; qi < 2; ++qi) {
    float rl[4];
#pragma unroll
    for (int r = 0; r < 4; ++r) {
      float s4 = Lp[qi][r];
#pragma unroll
      for (int m = 1; m < 16; m <<= 1) s4 += __shfl_xor(s4, m, 64);
      rl[r] = 1.0f / s4;
    }
#pragma unroll
    for (int db = 0; db < 8; ++db) {
      int d = db * 16 + lr;
#pragma unroll
      for (int r = 0; r < 4; ++r) {
        int q = qw0 + qi * 16 + lg * 4 + r;
        float obf16 = bf16_to_f32(bf16_rne(oacc[qi][db][r] * rl[r]));
        __half hh = __float2half(obf16);
        obf[(size_t)q * 2048 + h * 128 + d] = *(u16*)&hh;
      }
    }
  }
}

// ---------- launch ----------
extern "C" void kernel_launch(void* const* d_in, const int* in_sizes, int n_in,
                              void* d_out, int out_size, void* d_ws, size_t ws_size,
                              hipStream_t stream) {
  const float* x      = (const float*)d_in[0];
  const float* qkv_w  = (const float*)d_in[1];
  const float* qkv_b  = (const float*)d_in[2];
  const float* qnw    = (const float*)d_in[3];
  const float* knw    = (const float*)d_in[4];
  const float* proj_w = (const float*)d_in[5];
  const float* proj_b = (const float*)d_in[6];
  float* out = (float*)d_out;
  char* ws = (char*)d_ws;

  u16* xh    = (u16*)(ws + OFF_XSPLIT);   // fp16 x
  u16* wh    = (u16*)(ws + OFF_WSPLIT);   // fp16 qkv_w
  u16* pwh   = (u16*)(ws + OFF_WSPLIT);   // fp16 proj_w (overwrites wh AFTER QKV GEMM)
  float* qkf = (float*)(ws + OFF_QKF);
  u16* vb16  = (u16*)(ws + OFF_VB);
  u16* qb16  = (u16*)(ws + OFF_QB);
  u16* kb16  = (u16*)(ws + OFF_KB);
  u16* vt16  = (u16*)(ws + OFF_VT);
  u16* obf   = (u16*)(ws + OFF_XSPLIT);   // fp16 o, reuse (x dead after QKV GEMM)
  float* cosT = (float*)(ws + OFF_COS);
  float* sinT = (float*)(ws + OFF_SIN);

  // fused prep (vectorized): fp16 converts + rope table
  k_prep<<<2048, 256, 0, stream>>>(x, xh, qkv_w, wh, cosT, sinT);

  // QKV: single-segment fp16
  k_gemm_qkv16<<<dim3(48, 32), 256, 0, stream>>>(xh, wh, qkv_b, qkf, vb16);

  k_cvt16<<<2048, 256, 0, stream>>>(proj_w, pwh, 2048 * 2048 / 4);
  k_norm_rope<<<16384, 256, 0, stream>>>(qkf, qnw, knw, cosT, sinT, qb16, kb16);
  k_transpose_v<<<dim3(64, 16), 256, 0, stream>>>(vb16, vt16);
  k_attn<<<dim3(32, 16), 256, 0, stream>>>(qb16, kb16, vt16, obf);

  // proj: fp16 single segment
  k_gemm_proj<<<dim3(16, 32), 256, 0, stream>>>(obf, pwh, proj_b, out);
}

// Round 19
// 434.653 us; speedup vs baseline: 1.8332x; 1.0258x over previous
//
#include <hip/hip_runtime.h>
#include <hip/hip_bf16.h>
#include <hip/hip_fp16.h>

typedef unsigned short u16;
typedef unsigned int u32;
typedef __attribute__((ext_vector_type(8))) short s16x8;
typedef __attribute__((ext_vector_type(8))) _Float16 f16x8;
typedef __attribute__((ext_vector_type(4))) float f32x4;
typedef __attribute__((ext_vector_type(2))) float f32x2;
typedef __attribute__((ext_vector_type(4))) unsigned short u16x4;

#define DEV static __device__ __forceinline__

// ---------- helpers ----------
DEV u16 bf16_rne(float f) {
  u32 u = __float_as_uint(f);
  u32 r = 0x7FFFu + ((u >> 16) & 1u);
  return (u16)((u + r) >> 16);
}
DEV float bf16_to_f32(u16 h) { return __uint_as_float(((u32)h) << 16); }

typedef const __attribute__((address_space(1))) u32* gptr_t;
typedef __attribute__((address_space(3))) u32* lptr_t;
DEV void gload_lds16(const void* g, void* l) {
  __builtin_amdgcn_global_load_lds((gptr_t)g, (lptr_t)l, 16, 0, 0);
}

// ---------- workspace layout (bytes) ----------
#define OFF_XSPLIT  0ull                 // fp16 x (16.8 MB) ; reused as obf (fp16)
#define OFF_WSPLIT  33554432ull          // fp16 qkv_w (25.2 MB) ; reused as pwh (fp16)
#define OFF_QKF     83886080ull          // 4096*4096 f32 ([q|k] fp32)
#define OFF_VB      150994944ull         // v bf16 (n,h,d)
#define OFF_QB      167772160ull         // q bf16 (h,n,d)
#define OFF_KB      184549376ull         // k bf16 (h,n,d)
#define OFF_VT      201326592ull         // v bf16 (h,d,n)
#define OFF_COS     218103808ull
#define OFF_SIN     219152384ull

// ---------- fused prep: x -> fp16, qkv_w -> fp16, RoPE table. Vectorized. ----------
__global__ __launch_bounds__(256) void k_prep(
    const float* __restrict__ x,  u16* __restrict__ xh,
    const float* __restrict__ qw, u16* __restrict__ wh,
    float* __restrict__ cosT, float* __restrict__ sinT)
{
  const int tid0 = blockIdx.x * 256 + threadIdx.x;
  const int stride = gridDim.x * 256;

  for (int i = tid0; i < 4096 * 2048 / 4; i += stride) {
    f32x4 v = *(const f32x4*)(x + (size_t)i * 4);
    u16x4 o;
#pragma unroll
    for (int j = 0; j < 4; ++j) {
      __half h = __float2half(v[j]);
      o[j] = *(u16*)&h;
    }
    *(u16x4*)(xh + (size_t)i * 4) = o;
  }
  for (int i = tid0; i < 6144 * 2048 / 4; i += stride) {
    f32x4 v = *(const f32x4*)(qw + (size_t)i * 4);
    u16x4 o;
#pragma unroll
    for (int j = 0; j < 4; ++j) {
      __half h = __float2half(v[j]);
      o[j] = *(u16*)&h;
    }
    *(u16x4*)(wh + (size_t)i * 4) = o;
  }
  for (int i = tid0; i < 4096 * 64; i += stride) {
    int n = i >> 6, j = i & 63;
    int t = n >> 9, hh = (n >> 5) & 15, ww = n & 31;
    float pos, e;
    if (j < 32)      { pos = (float)t;  e = (float)j * (1.0f / 32.0f); }
    else if (j < 48) { pos = (float)hh; e = (float)(j - 32) * (1.0f / 16.0f); }
    else             { pos = (float)ww; e = (float)(j - 48) * (1.0f / 16.0f); }
    float inv = (float)pow(10000.0, -(double)e);
    float f = pos * inv;
    cosT[i] = cosf(f);
    sinT[i] = sinf(f);
  }
}

// ---------- fp32 -> fp16 convert (RNE) ----------
__global__ __launch_bounds__(256) void k_cvt16(const float* __restrict__ in,
                                               u16* __restrict__ out, int n4) {
  int i = blockIdx.x * 256 + threadIdx.x;
  int stride = gridDim.x * 256;
  for (; i < n4; i += stride) {
    f32x4 v = *(const f32x4*)(in + (size_t)i * 4);
    u16x4 o;
#pragma unroll
    for (int j = 0; j < 4; ++j) {
      __half h = __float2half(v[j]);
      o[j] = *(u16*)&h;
    }
    *(u16x4*)(out + (size_t)i * 4) = o;
  }
}

// ---------- QKV GEMM: single-segment fp16, k-block unroll x2 (two buffer sets) ----------
__global__ __launch_bounds__(256, 2) void k_gemm_qkv16(
    const u16* __restrict__ A, const u16* __restrict__ B,
    const float* __restrict__ bias,
    float* __restrict__ outF, u16* __restrict__ outV)
{
  __shared__ u16 As[2][128 * 32];
  __shared__ u16 Bs[2][128 * 32];
  const int t = threadIdx.x;
  const int lane = t & 63;
  const int lr = lane & 15, lg = lane >> 4;
  const int w = t >> 6;
  const int wr = w >> 1, wc = w & 1;
  const int row0 = blockIdx.y * 128;
  const int col0 = blockIdx.x * 128;
  const int K = 2048;

  f32x4 acc[4][4];
#pragma unroll
  for (int m = 0; m < 4; m++)
#pragma unroll
    for (int n = 0; n < 4; n++) acc[m][n] = f32x4{0.f, 0.f, 0.f, 0.f};

  const int c0 = t, c1 = t + 256;
  const int kp0 = ((c0 & 3) ^ ((c0 >> 3) & 3)) * 8;
  const int kp1 = ((c1 & 3) ^ ((c1 >> 3) & 3)) * 8;
  const int slot8 = (lg ^ ((lr >> 1) & 3)) * 8;
  const size_t ar0 = (size_t)(row0 + (c0 >> 2)) * K;
  const size_t ar1 = (size_t)(row0 + (c1 >> 2)) * K;
  const size_t br0 = (size_t)(col0 + (c0 >> 2)) * K;
  const size_t br1 = (size_t)(col0 + (c1 >> 2)) * K;

  for (int kb = 0; kb < 64; kb += 2) {
#pragma unroll
    for (int u = 0; u < 2; ++u) {
      const int k0 = (kb + u) * 32;
      gload_lds16(A + ar0 + k0 + kp0, &As[u][c0 * 8]);
      gload_lds16(A + ar1 + k0 + kp1, &As[u][c1 * 8]);
      gload_lds16(B + br0 + k0 + kp0, &Bs[u][c0 * 8]);
      gload_lds16(B + br1 + k0 + kp1, &Bs[u][c1 * 8]);
    }
    __syncthreads();
#pragma unroll
    for (int u = 0; u < 2; ++u) {
      f16x8 af[4], bf[4];
#pragma unroll
      for (int m = 0; m < 4; m++)
        af[m] = *(const f16x8*)&As[u][(wr * 64 + m * 16 + lr) * 32 + slot8];
#pragma unroll
      for (int n = 0; n < 4; n++)
        bf[n] = *(const f16x8*)&Bs[u][(wc * 64 + n * 16 + lr) * 32 + slot8];
      __builtin_amdgcn_s_setprio(1);
#pragma unroll
      for (int m = 0; m < 4; m++)
#pragma unroll
        for (int n = 0; n < 4; n++)
          acc[m][n] = __builtin_amdgcn_mfma_f32_16x16x32_f16(af[m], bf[n], acc[m][n], 0, 0, 0);
      __builtin_amdgcn_s_setprio(0);
    }
    __syncthreads();
  }

#pragma unroll
  for (int m = 0; m < 4; m++) {
#pragma unroll
    for (int n = 0; n < 4; n++) {
      int col = col0 + wc * 64 + n * 16 + lr;
      float b = bias[col];
#pragma unroll
      for (int r = 0; r < 4; r++) {
        int row = row0 + wr * 64 + m * 16 + lg * 4 + r;
        float v = acc[m][n][r] + b;
        if (col < 4096) outF[(size_t)row * 4096 + col] = v;
        else            outV[(size_t)row * 2048 + (col - 4096)] = bf16_rne(v);
      }
    }
  }
}

// ---------- proj GEMM: fp16 single segment, k-block unroll x2 ----------
__global__ __launch_bounds__(256, 2) void k_gemm_proj(
    const u16* __restrict__ A, const u16* __restrict__ B,
    const float* __restrict__ bias, float* __restrict__ outF)
{
  __shared__ u16 As[2][128 * 32];
  __shared__ u16 Bs[2][128 * 32];
  const int t = threadIdx.x;
  const int lane = t & 63;
  const int lr = lane & 15, lg = lane >> 4;
  const int w = t >> 6;
  const int wr = w >> 1, wc = w & 1;
  const int row0 = blockIdx.y * 128;
  const int col0 = blockIdx.x * 128;
  const int K = 2048;

  f32x4 acc[4][4];
#pragma unroll
  for (int m = 0; m < 4; m++)
#pragma unroll
    for (int n = 0; n < 4; n++) acc[m][n] = f32x4{0.f, 0.f, 0.f, 0.f};

  const int c0 = t, c1 = t + 256;
  const int kp0 = ((c0 & 3) ^ ((c0 >> 3) & 3)) * 8;
  const int kp1 = ((c1 & 3) ^ ((c1 >> 3) & 3)) * 8;
  const int slot8 = (lg ^ ((lr >> 1) & 3)) * 8;
  const size_t ar0 = (size_t)(row0 + (c0 >> 2)) * K;
  const size_t ar1 = (size_t)(row0 + (c1 >> 2)) * K;
  const size_t br0 = (size_t)(col0 + (c0 >> 2)) * K;
  const size_t br1 = (size_t)(col0 + (c1 >> 2)) * K;

  for (int kb = 0; kb < 64; kb += 2) {
#pragma unroll
    for (int u = 0; u < 2; ++u) {
      const int k0 = (kb + u) * 32;
      gload_lds16(A + ar0 + k0 + kp0, &As[u][c0 * 8]);
      gload_lds16(A + ar1 + k0 + kp1, &As[u][c1 * 8]);
      gload_lds16(B + br0 + k0 + kp0, &Bs[u][c0 * 8]);
      gload_lds16(B + br1 + k0 + kp1, &Bs[u][c1 * 8]);
    }
    __syncthreads();
#pragma unroll
    for (int u = 0; u < 2; ++u) {
      f16x8 af[4], bf[4];
#pragma unroll
      for (int m = 0; m < 4; m++)
        af[m] = *(const f16x8*)&As[u][(wr * 64 + m * 16 + lr) * 32 + slot8];
#pragma unroll
      for (int n = 0; n < 4; n++)
        bf[n] = *(const f16x8*)&Bs[u][(wc * 64 + n * 16 + lr) * 32 + slot8];
      __builtin_amdgcn_s_setprio(1);
#pragma unroll
      for (int m = 0; m < 4; m++)
#pragma unroll
        for (int n = 0; n < 4; n++)
          acc[m][n] = __builtin_amdgcn_mfma_f32_16x16x32_f16(af[m], bf[n], acc[m][n], 0, 0, 0);
      __builtin_amdgcn_s_setprio(0);
    }
    __syncthreads();
  }

#pragma unroll
  for (int m = 0; m < 4; m++) {
#pragma unroll
    for (int n = 0; n < 4; n++) {
      int col = col0 + wc * 64 + n * 16 + lr;
      float b = bias[col];
#pragma unroll
      for (int r = 0; r < 4; r++) {
        int row = row0 + wr * 64 + m * 16 + lg * 4 + r;
        outF[(size_t)row * 2048 + col] = acc[m][n][r] + b;
      }
    }
  }
}

// ---------- RMSNorm (fp32) + RoPE + bf16 cast for q,k. One wave per (n,h). ----------
__global__ __launch_bounds__(256) void k_norm_rope(
    const float* __restrict__ qkf, const float* __restrict__ qw, const float* __restrict__ kw,
    const float* __restrict__ cosT, const float* __restrict__ sinT,
    u16* __restrict__ qb, u16* __restrict__ kb)
{
  int gw = (blockIdx.x * 256 + threadIdx.x) >> 6;
  int lane = threadIdx.x & 63;
  int n = gw >> 4;
  int h = gw & 15;
  float c = cosT[n * 64 + lane];
  float s = sinT[n * 64 + lane];
#pragma unroll
  for (int p = 0; p < 2; ++p) {
    const float* src = qkf + (size_t)n * 4096 + p * 2048 + h * 128;
    f32x2 xv = *(const f32x2*)(src + lane * 2);
    float xr = xv[0], xi = xv[1];
    float ss = xr * xr + xi * xi;
#pragma unroll
    for (int m = 1; m < 64; m <<= 1) ss += __shfl_xor(ss, m, 64);
    float r = 1.0f / sqrtf(ss * (1.0f / 128.0f) + 1e-6f);
    const float* wgt = p ? kw : qw;
    float yr = xr * r * wgt[lane * 2];
    float yi = xi * r * wgt[lane * 2 + 1];
    float o0 = yr * c - yi * s;
    float o1 = yr * s + yi * c;
    u16* dst = (p ? kb : qb) + (size_t)h * 4096 * 128 + (size_t)n * 128 + lane * 2;
    *(u32*)dst = ((u32)bf16_rne(o1) << 16) | bf16_rne(o0);
  }
}

// ---------- V transpose: (n, h*128+d) -> (h, d, n) ----------
__global__ __launch_bounds__(256) void k_transpose_v(const u16* __restrict__ vb, u16* __restrict__ vt) {
  __shared__ u16 Vs[64][136];
  int h = blockIdx.y;
  int n0 = blockIdx.x * 64;
  int t = threadIdx.x;
  int nl = t >> 2, d0 = (t & 3) * 32;
  const u16* src = vb + (size_t)(n0 + nl) * 2048 + h * 128 + d0;
#pragma unroll
  for (int i = 0; i < 8; ++i)
    *(u16x4*)&Vs[nl][d0 + i * 4] = *(const u16x4*)(src + i * 4);
  __syncthreads();
  int d = t >> 1, nc = (t & 1) * 32;
  u16* dst = vt + (size_t)h * 128 * 4096 + (size_t)d * 4096 + n0 + nc;
#pragma unroll
  for (int j4 = 0; j4 < 8; ++j4) {
    u16x4 o;
    o.x = Vs[nc + j4 * 4 + 0][d];
    o.y = Vs[nc + j4 * 4 + 1][d];
    o.z = Vs[nc + j4 * 4 + 2][d];
    o.w = Vs[nc + j4 * 4 + 3][d];
    *(u16x4*)(dst + j4 * 4) = o;
  }
}

// ---------- flash attention: r16 proven kernel (no-max softmax, deferred L) ----------
__global__ __launch_bounds__(256, 2) void k_attn(
    const u16* __restrict__ qb, const u16* __restrict__ kb, const u16* __restrict__ vt,
    u16* __restrict__ obf)
{
  __shared__ u16 Ks[2][64 * 128];
  __shared__ u16 Vs[2][128 * 64];
  __shared__ u16 Ps[4][32 * 64];
  const int t = threadIdx.x;
  const int lane = t & 63;
  const int lr = lane & 15, lg = lane >> 4;
  const int w = t >> 6;

  const int bid = blockIdx.y * 32 + blockIdx.x;
  const int h = (bid & 7) + 8 * ((bid >> 3) >> 5);
  const int qt = (bid >> 3) & 31;
  const int qw0 = qt * 128 + w * 32;

  const u16* qh = qb + (size_t)h * 4096 * 128;
  const u16* kh = kb + (size_t)h * 4096 * 128;
  const u16* vh = vt + (size_t)h * 128 * 4096;

  s16x8 qf[2][4];
#pragma unroll
  for (int qi = 0; qi < 2; ++qi)
#pragma unroll
    for (int ks = 0; ks < 4; ++ks)
      qf[qi][ks] = *(const s16x8*)(qh + (size_t)(qw0 + qi * 16 + lr) * 128 + ks * 32 + lg * 8);

  f32x4 oacc[2][8];
#pragma unroll
  for (int i = 0; i < 2; i++)
#pragma unroll
    for (int j = 0; j < 8; j++) oacc[i][j] = f32x4{0.f, 0.f, 0.f, 0.f};
  float Lp[2][4];
#pragma unroll
  for (int i = 0; i < 2; i++)
#pragma unroll
    for (int r = 0; r < 4; r++) Lp[i][r] = 0.f;

  const float scale_bf = bf16_to_f32(bf16_rne(0.08838834764831845f));

  auto stageKV = [&](int kt, int b) __attribute__((always_inline)) {
#pragma unroll
    for (int i = 0; i < 4; ++i) {
      int c = t + i * 256;
      int row = c >> 4;
      int cc = (c & 15) ^ (row & 7);
      gload_lds16(kh + (size_t)(kt * 64 + row) * 128 + cc * 8, &Ks[b][c * 8]);
    }
#pragma unroll
    for (int i = 0; i < 4; ++i) {
      int c = t + i * 256;
      int d = c >> 3;
      int cc = (c & 7) ^ (d & 7);
      gload_lds16(vh + (size_t)d * 4096 + kt * 64 + cc * 8, &Vs[b][c * 8]);
    }
  };

  stageKV(0, 0);
  __syncthreads();

  for (int kt = 0; kt < 64; ++kt) {
    const int b = kt & 1;
    if (kt + 1 < 64) stageKV(kt + 1, b ^ 1);

    f32x4 sfr[2][4];
    __builtin_amdgcn_s_setprio(1);
#pragma unroll
    for (int qi = 0; qi < 2; ++qi)
#pragma unroll
      for (int kbl = 0; kbl < 4; ++kbl) {
        f32x4 a = f32x4{0.f, 0.f, 0.f, 0.f};
#pragma unroll
        for (int ks = 0; ks < 4; ++ks) {
          int key = kbl * 16 + lr;
          int byteoff = (key * 256 + (ks * 32 + lg * 8) * 2) ^ ((key & 7) << 4);
          s16x8 bfr = *(const s16x8*)((const char*)&Ks[b][0] + byteoff);
          a = __builtin_amdgcn_mfma_f32_16x16x32_bf16(qf[qi][ks], bfr, a, 0, 0, 0);
        }
        sfr[qi][kbl] = a;
      }
    __builtin_amdgcn_s_setprio(0);

    // no-max softmax: p = exp(bf16(bf16(s)*scale)); hand-rolled RNE (proven path)
#pragma unroll
    for (int qi = 0; qi < 2; ++qi)
#pragma unroll
      for (int kbl = 0; kbl < 4; ++kbl)
#pragma unroll
        for (int r = 0; r < 4; ++r) {
          float sv = bf16_to_f32(bf16_rne(sfr[qi][kbl][r])) * scale_bf;
          float p = __expf(bf16_to_f32(bf16_rne(sv)));
          Lp[qi][r] += p;
          int prow = qi * 16 + lg * 4 + r;
          Ps[w][prow * 64 + ((kbl * 16 + lr) ^ (((lg * 4 + r) & 7) << 3))] = bf16_rne(p);
        }

    asm volatile("s_waitcnt lgkmcnt(0)" ::: "memory");   // own-wave P writes visible

    s16x8 pa[2][2];
#pragma unroll
    for (int qi = 0; qi < 2; ++qi)
#pragma unroll
      for (int ks = 0; ks < 2; ++ks) {
        int prow = qi * 16 + lr;
        pa[qi][ks] = *(const s16x8*)&Ps[w][prow * 64 + ((ks * 32 + lg * 8) ^ ((lr & 7) << 3))];
      }
    __builtin_amdgcn_s_setprio(1);
#pragma unroll
    for (int db = 0; db < 8; ++db)
#pragma unroll
      for (int ks = 0; ks < 2; ++ks) {
        int d = db * 16 + lr;
        int byteoff = (d * 128 + (ks * 32 + lg * 8) * 2) ^ ((d & 7) << 4);
        s16x8 vb8 = *(const s16x8*)((const char*)&Vs[b][0] + byteoff);
        oacc[0][db] = __builtin_amdgcn_mfma_f32_16x16x32_bf16(pa[0][ks], vb8, oacc[0][db], 0, 0, 0);
        oacc[1][db] = __builtin_amdgcn_mfma_f32_16x16x32_bf16(pa[1][ks], vb8, oacc[1][db], 0, 0, 0);
      }
    __builtin_amdgcn_s_setprio(0);
    __syncthreads();
  }

  // deferred L reduction (once), then normalize + bf16 round + fp16-bit store
#pragma unroll
  for (int qi = 0; qi < 2; ++qi) {
    float rl[4];
#pragma unroll
    for (int r = 0; r < 4; ++r) {
      float s4 = Lp[qi][r];
#pragma unroll
      for (int m = 1; m < 16; m <<= 1) s4 += __shfl_xor(s4, m, 64);
      rl[r] = 1.0f / s4;
    }
#pragma unroll
    for (int db = 0; db < 8; ++db) {
      int d = db * 16 + lr;
#pragma unroll
      for (int r = 0; r < 4; ++r) {
        int q = qw0 + qi * 16 + lg * 4 + r;
        float obf16 = bf16_to_f32(bf16_rne(oacc[qi][db][r] * rl[r]));
        __half hh = __float2half(obf16);
        obf[(size_t)q * 2048 + h * 128 + d] = *(u16*)&hh;
      }
    }
  }
}

// ---------- launch ----------
extern "C" void kernel_launch(void* const* d_in, const int* in_sizes, int n_in,
                              void* d_out, int out_size, void* d_ws, size_t ws_size,
                              hipStream_t stream) {
  const float* x      = (const float*)d_in[0];
  const float* qkv_w  = (const float*)d_in[1];
  const float* qkv_b  = (const float*)d_in[2];
  const float* qnw    = (const float*)d_in[3];
  const float* knw    = (const float*)d_in[4];
  const float* proj_w = (const float*)d_in[5];
  const float* proj_b = (const float*)d_in[6];
  float* out = (float*)d_out;
  char* ws = (char*)d_ws;

  u16* xh    = (u16*)(ws + OFF_XSPLIT);
  u16* wh    = (u16*)(ws + OFF_WSPLIT);
  u16* pwh   = (u16*)(ws + OFF_WSPLIT);   // fp16 proj_w (overwrites wh AFTER QKV GEMM)
  float* qkf = (float*)(ws + OFF_QKF);
  u16* vb16  = (u16*)(ws + OFF_VB);
  u16* qb16  = (u16*)(ws + OFF_QB);
  u16* kb16  = (u16*)(ws + OFF_KB);
  u16* vt16  = (u16*)(ws + OFF_VT);
  u16* obf   = (u16*)(ws + OFF_XSPLIT);   // fp16 o, reuse (x dead after QKV GEMM)
  float* cosT = (float*)(ws + OFF_COS);
  float* sinT = (float*)(ws + OFF_SIN);

  // fused prep (vectorized): fp16 converts + rope table
  k_prep<<<2048, 256, 0, stream>>>(x, xh, qkv_w, wh, cosT, sinT);

  // QKV: single-segment fp16, k-unroll x2
  k_gemm_qkv16<<<dim3(48, 32), 256, 0, stream>>>(xh, wh, qkv_b, qkf, vb16);

  k_cvt16<<<2048, 256, 0, stream>>>(proj_w, pwh, 2048 * 2048 / 4);
  k_norm_rope<<<16384, 256, 0, stream>>>(qkf, qnw, knw, cosT, sinT, qb16, kb16);
  k_transpose_v<<<dim3(64, 16), 256, 0, stream>>>(vb16, vt16);
  k_attn<<<dim3(32, 16), 256, 0, stream>>>(qb16, kb16, vt16, obf);

  // proj: fp16 single segment, k-unroll x2
  k_gemm_proj<<<dim3(16, 32), 256, 0, stream>>>(obf, pwh, proj_b, out);
}